// Round 14
// baseline (429.690 us; speedup 1.0000x reference)
//
#include <hip/hip_runtime.h>

#define N_NODES 100000
#define N_EDGES 800000
#define N_ETYPES 5
#define NUM_GRAPHS 64
#define IN_DIM 23
#define HID_DIM 128
#define OUT_DIM 64
#define N_KEYS (N_NODES * N_ETYPES)      // 500,000  (key = dst*5 + t)
#define KPB 2048                         // keys per bin
#define NBINS ((N_KEYS + KPB - 1) / KPB) // 245
#define BIN_CAP 18432                    // Poisson(16384) + 16 sigma
#define CHUNK 8192                       // edges per k_bin block
#define TOT_EDGES (N_EDGES * N_ETYPES)   // 4,000,000
#define BIN_BLOCKS ((TOT_EDGES + CHUNK - 1) / CHUNK)  // 489
#define PREP_BLOCKS 64

typedef unsigned short u16;
typedef unsigned int u32;
using short8 = __attribute__((ext_vector_type(8))) short;
using f32x4  = __attribute__((ext_vector_type(4))) float;

__device__ __forceinline__ float bf2f(u16 v) {
    union { unsigned u; float f; } x; x.u = ((unsigned)v) << 16; return x.f;
}
__device__ __forceinline__ float lo2f(u32 v) {
    union { unsigned u; float f; } x; x.u = v << 16; return x.f;
}
__device__ __forceinline__ float hi2f(u32 v) {
    union { unsigned u; float f; } x; x.u = v & 0xffff0000u; return x.f;
}
__device__ __forceinline__ u16 f2bf(float f) {
    union { float f; unsigned u; } x; x.f = f;
    unsigned r = x.u + 0x7fff + ((x.u >> 16) & 1);   // RNE
    return (u16)(r >> 16);
}

// ---------------- pass A: bin edges by key>>11 (blocks 0..488); prep work (489..552) -------
__global__ __launch_bounds__(256) void k_bin(const int* __restrict__ edges,
                                             int* __restrict__ bin_cnt,
                                             int* __restrict__ binned,
                                             const float* __restrict__ W1,
                                             const float* __restrict__ W2,
                                             const float* __restrict__ b1,
                                             const float* __restrict__ x,
                                             u16* __restrict__ w1t,
                                             u16* __restrict__ w2t,
                                             float* __restrict__ b1s,
                                             u16* __restrict__ xb) {
    __shared__ int s_key[CHUNK];      // 32 KB
    __shared__ int s_hist[4][256];    // 4 KB (per-wave)
    __shared__ int s_base[4][256];    // 4 KB (per-wave running offsets)
    int tid = threadIdx.x;

    if (blockIdx.x >= BIN_BLOCKS) {   // ---- fused prep (independent of binning) ----
        int stride = PREP_BLOCKS * 256;
        int g0 = (blockIdx.x - BIN_BLOCKS) * 256 + tid;
        for (int i = g0; i < HID_DIM * 160; i += stride) {       // w1t[hid][k], k=t*32+f
            int hid = i / 160, k = i - hid * 160;
            int t = k >> 5, f = k & 31;
            w1t[i] = (f < IN_DIM) ? f2bf(W1[((size_t)t * IN_DIM + f) * HID_DIM + hid]) : (u16)0;
        }
        for (int i = g0; i < N_ETYPES * OUT_DIM * HID_DIM; i += stride) { // w2t[t][out][k]
            int t = i >> 13, r = i & 8191;
            int out = r >> 7, k = r & 127;
            w2t[i] = f2bf(W2[((size_t)t * HID_DIM + k) * OUT_DIM + out]);
        }
        for (int i = g0; i < HID_DIM; i += stride) {
            float s = 0.f;
            #pragma unroll
            for (int t = 0; t < N_ETYPES; ++t) s += b1[t * HID_DIM + i];
            b1s[i] = s;
        }
        for (int i = g0; i < N_NODES * 32; i += stride) {        // xb padded to 32 cols
            int n = i >> 5, f = i & 31;
            xb[i] = (f < IN_DIM) ? f2bf(x[(size_t)n * IN_DIM + f]) : (u16)0;
        }
        return;
    }

    int w = tid >> 6;
    int g0 = blockIdx.x * CHUNK;
    int nch = TOT_EDGES - g0; if (nch > CHUNK) nch = CHUNK;
    for (int i = tid; i < 4 * 256; i += 256) ((int*)s_hist)[i] = 0;
    __syncthreads();
    // sweep 1: read dst, per-wave histogram, stash keys
    for (int i = tid; i < nch; i += 256) {
        int gi = g0 + i;
        int t = (unsigned)gi / (unsigned)N_EDGES;          // const divisor -> magic mul
        int e = gi - t * N_EDGES;
        int dst = edges[((size_t)t * 2 + 1) * N_EDGES + e];
        int key = dst * N_ETYPES + t;
        s_key[i] = key;
        atomicAdd(&s_hist[w][key >> 11], 1);
    }
    __syncthreads();
    // reserve: one global atomic per non-empty (block, bin); per-wave sub-bases
    for (int i = tid; i < NBINS; i += 256) {
        int h0 = s_hist[0][i], h1 = s_hist[1][i], h2 = s_hist[2][i], h3 = s_hist[3][i];
        int h = h0 + h1 + h2 + h3;
        int base = h ? atomicAdd(&bin_cnt[i], h) : 0;
        s_base[0][i] = base;
        s_base[1][i] = base + h0;
        s_base[2][i] = base + h0 + h1;
        s_base[3][i] = base + h0 + h1 + h2;
    }
    __syncthreads();
    // sweep 2: read src, place entries (same thread -> same edges as sweep 1)
    for (int i = tid; i < nch; i += 256) {
        int gi = g0 + i;
        int t = (unsigned)gi / (unsigned)N_EDGES;
        int e = gi - t * N_EDGES;
        int src = edges[((size_t)t * 2 + 0) * N_EDGES + e];
        int key = s_key[i];
        int bin = key >> 11;
        int pos = atomicAdd(&s_base[w][bin], 1);
        if (pos < BIN_CAP)
            binned[(size_t)bin * BIN_CAP + pos] = ((key & 2047) << 17) | src;
    }
}

// ---------------- pass B: per-bin counting sort -> rowptr + CSR ----------------
__global__ __launch_bounds__(256) void k_csr(const int* __restrict__ bin_cnt,
                                             const int* __restrict__ binned,
                                             int* __restrict__ rowptr,
                                             int* __restrict__ csr) {
    __shared__ int s_cnt[KPB];        // 8 KB
    __shared__ int s_ofs[KPB];        // 8 KB
    __shared__ int s_red[256];
    int tid = threadIdx.x;
    int b = blockIdx.x;
    // csr_base = sum bin_cnt[0..b)
    int ps = 0;
    for (int i = tid; i < b; i += 256) ps += bin_cnt[i];
    s_red[tid] = ps;
    __syncthreads();
    for (int s = 128; s > 0; s >>= 1) {
        if (tid < s) s_red[tid] += s_red[tid + s];
        __syncthreads();
    }
    int csr_base = s_red[0];
    __syncthreads();
    int cnt_b = bin_cnt[b];
    if (cnt_b > BIN_CAP) cnt_b = BIN_CAP;
    int key0 = b * KPB;
    int keys_in = N_KEYS - key0; if (keys_in > KPB) keys_in = KPB;
    for (int i = tid; i < KPB; i += 256) s_cnt[i] = 0;
    __syncthreads();
    const int* ep = binned + (size_t)b * BIN_CAP;
    for (int i = tid; i < cnt_b; i += 256)
        atomicAdd(&s_cnt[ep[i] >> 17], 1);
    __syncthreads();
    // exclusive scan over 2048 counters: 8/thread serial + block Hillis-Steele
    int loc[8]; int base_t = 0;
    #pragma unroll
    for (int q = 0; q < 8; ++q) { loc[q] = base_t; base_t += s_cnt[tid * 8 + q]; }
    s_red[tid] = base_t;
    __syncthreads();
    for (int s = 1; s < 256; s <<= 1) {
        int add = (tid >= s) ? s_red[tid - s] : 0;
        __syncthreads();
        s_red[tid] += add;
        __syncthreads();
    }
    int excl = (tid == 0) ? 0 : s_red[tid - 1];
    #pragma unroll
    for (int q = 0; q < 8; ++q) {
        int k = tid * 8 + q;
        int o = excl + loc[q];
        s_ofs[k] = o;
        if (k < keys_in) rowptr[key0 + k] = csr_base + o;
    }
    if (b == NBINS - 1 && tid == 0) rowptr[N_KEYS] = csr_base + cnt_b;
    __syncthreads();
    // scatter into CSR (writes land in a 64KB L2-hot window)
    for (int i = tid; i < cnt_b; i += 256) {
        int entry = ep[i];
        int pos = atomicAdd(&s_ofs[entry >> 17], 1);
        csr[csr_base + pos] = entry & 0x1FFFF;
    }
}

// ------ layer-1 gather: 8-lane group per (node,etype); lane owns uint2 (4 bf16 cols).
// ------ No cross-lane fold needed. kmax group-uniform => shfl always uniform.
__global__ __launch_bounds__(256) void k_gather1(const int* __restrict__ rowptr,
                                                 const int* __restrict__ csr,
                                                 const u32* __restrict__ xb32,
                                                 u32* __restrict__ acat32) {
    int tid = threadIdx.x;
    int fl = tid & 7;                         // uint2 index within 64B row
    int lanebase = tid & 56;                  // 8-lane group base within wave
    int n = blockIdx.x * 32 + (tid >> 3);     // 32 nodes per block
    int t = blockIdx.y;
    int key = n * N_ETYPES + t;
    int rp0 = rowptr[key];
    int deg = rowptr[key + 1] - rp0;
    int stageA = csr[rp0 + fl];               // entries 0..7
    int stageB = csr[rp0 + 8 + fl];           // entries 8..15 (csr padded)
    int kmax = deg < 16 ? deg : 16;
    int kA = kmax < 8 ? kmax : 8;
    uint2 v = *(const uint2*)&xb32[(size_t)n * 16 + fl * 2];   // self (pad cols zero)
    float a0 = lo2f(v.x), a1 = hi2f(v.x), a2 = lo2f(v.y), a3 = hi2f(v.y);
    float b0 = 0.f, b1v = 0.f, b2 = 0.f, b3 = 0.f;
    int k = 0;
    for (; k + 3 < kA; k += 4) {              // phase A: 4 rows in flight
        int s0 = __shfl(stageA, lanebase + k);
        int s1 = __shfl(stageA, lanebase + k + 1);
        int s2 = __shfl(stageA, lanebase + k + 2);
        int s3 = __shfl(stageA, lanebase + k + 3);
        uint2 v0 = *(const uint2*)&xb32[(size_t)s0 * 16 + fl * 2];
        uint2 v1 = *(const uint2*)&xb32[(size_t)s1 * 16 + fl * 2];
        uint2 v2 = *(const uint2*)&xb32[(size_t)s2 * 16 + fl * 2];
        uint2 v3 = *(const uint2*)&xb32[(size_t)s3 * 16 + fl * 2];
        a0 += lo2f(v0.x); a1 += hi2f(v0.x); a2 += lo2f(v0.y); a3 += hi2f(v0.y);
        b0 += lo2f(v1.x); b1v += hi2f(v1.x); b2 += lo2f(v1.y); b3 += hi2f(v1.y);
        a0 += lo2f(v2.x); a1 += hi2f(v2.x); a2 += lo2f(v2.y); a3 += hi2f(v2.y);
        b0 += lo2f(v3.x); b1v += hi2f(v3.x); b2 += lo2f(v3.y); b3 += hi2f(v3.y);
    }
    for (; k < kA; ++k) {
        int s0 = __shfl(stageA, lanebase + k);
        uint2 v0 = *(const uint2*)&xb32[(size_t)s0 * 16 + fl * 2];
        a0 += lo2f(v0.x); a1 += hi2f(v0.x); a2 += lo2f(v0.y); a3 += hi2f(v0.y);
    }
    for (k = 8; k + 3 < kmax; k += 4) {       // phase B: entries 8..15
        int s0 = __shfl(stageB, lanebase + k - 8);
        int s1 = __shfl(stageB, lanebase + k - 7);
        int s2 = __shfl(stageB, lanebase + k - 6);
        int s3 = __shfl(stageB, lanebase + k - 5);
        uint2 v0 = *(const uint2*)&xb32[(size_t)s0 * 16 + fl * 2];
        uint2 v1 = *(const uint2*)&xb32[(size_t)s1 * 16 + fl * 2];
        uint2 v2 = *(const uint2*)&xb32[(size_t)s2 * 16 + fl * 2];
        uint2 v3 = *(const uint2*)&xb32[(size_t)s3 * 16 + fl * 2];
        a0 += lo2f(v0.x); a1 += hi2f(v0.x); a2 += lo2f(v0.y); a3 += hi2f(v0.y);
        b0 += lo2f(v1.x); b1v += hi2f(v1.x); b2 += lo2f(v1.y); b3 += hi2f(v1.y);
        a0 += lo2f(v2.x); a1 += hi2f(v2.x); a2 += lo2f(v2.y); a3 += hi2f(v2.y);
        b0 += lo2f(v3.x); b1v += hi2f(v3.x); b2 += lo2f(v3.y); b3 += hi2f(v3.y);
    }
    for (; k < kmax && k >= 8; ++k) {
        int s0 = __shfl(stageB, lanebase + k - 8);
        uint2 v0 = *(const uint2*)&xb32[(size_t)s0 * 16 + fl * 2];
        a0 += lo2f(v0.x); a1 += hi2f(v0.x); a2 += lo2f(v0.y); a3 += hi2f(v0.y);
    }
    for (k = 16; k < deg; ++k) {              // deg>16: rare; uniform broadcast loads
        int s0 = csr[rp0 + k];
        uint2 v0 = *(const uint2*)&xb32[(size_t)s0 * 16 + fl * 2];
        a0 += lo2f(v0.x); a1 += hi2f(v0.x); a2 += lo2f(v0.y); a3 += hi2f(v0.y);
    }
    a0 += b0; a1 += b1v; a2 += b2; a3 += b3;
    if (fl < 6) {
        float inv = 1.0f / (float)(deg + 1);
        uint2 o;
        o.x = (u32)f2bf(a0 * inv) | ((u32)f2bf(a1 * inv) << 16);
        o.y = (u32)f2bf(a2 * inv) | ((u32)f2bf(a3 * inv) << 16);
        *(uint2*)&acat32[(size_t)n * 60 + t * 12 + fl * 2] = o;
    }
}

// ---------------- fused GEMM chain: acat -> MFMA L1+relu (LDS) -> MFMA L2 -> g -------------
__global__ __launch_bounds__(256) void k_gemm12(const u16* __restrict__ acat,
                                                const u16* __restrict__ w1t,
                                                const u16* __restrict__ w2t,
                                                const float* __restrict__ b1s,
                                                u16* __restrict__ g,
                                                int gt0, int gt1) {
    __shared__ u16 s_a[64 * 168];     // [64][160+8]  21504 B  (reused as s_out)
    __shared__ u16 s_h1[64 * 136];    // [64][128+8]  17408 B
    u16* s_out = s_a;                 // dead after A-frags are in registers
    int tid = threadIdx.x;
    int base = blockIdx.x * 64;

    // stage acat tile: expand [120] packed -> [160] zero-padded (coalesced ushort4)
    for (int i = tid; i < 64 * 40; i += 256) {
        int r = i / 40, col4 = i - r * 40;
        int t = col4 >> 3, q4 = col4 & 7;
        ushort4 v = {0, 0, 0, 0};
        if (q4 < 6 && base + r < N_NODES)
            v = *(const ushort4*)&acat[(size_t)(base + r) * 120 + t * 24 + q4 * 4];
        *(ushort4*)&s_a[r * 168 + t * 32 + q4 * 4] = v;
    }
    __syncthreads();

    int l = tid & 63, w = tid >> 6;
    int lr = l & 15, lg = l >> 4;

    // ---- L1: h1 = relu(s_a @ W1t + b1s) ----
    short8 a5[5];
    #pragma unroll
    for (int ks = 0; ks < 5; ++ks)
        a5[ks] = *(const short8*)&s_a[(w * 16 + lr) * 168 + ks * 32 + lg * 8];
    {
        f32x4 acc[8];
        #pragma unroll
        for (int nt = 0; nt < 8; ++nt) acc[nt] = (f32x4){0.f, 0.f, 0.f, 0.f};
        #pragma unroll
        for (int nt = 0; nt < 8; ++nt) {
            #pragma unroll
            for (int ks = 0; ks < 5; ++ks) {
                short8 b = *(const short8*)&w1t[(nt * 16 + lr) * 160 + ks * 32 + lg * 8];
                acc[nt] = __builtin_amdgcn_mfma_f32_16x16x32_bf16(a5[ks], b, acc[nt], 0, 0, 0);
            }
        }
        #pragma unroll
        for (int nt = 0; nt < 8; ++nt) {
            float bias = b1s[nt * 16 + lr];
            #pragma unroll
            for (int r = 0; r < 4; ++r) {
                float h = acc[nt][r] + bias;
                s_h1[(w * 16 + lg * 4 + r) * 136 + nt * 16 + lr] = f2bf(h > 0.f ? h : 0.f);
            }
        }
    }
    __syncthreads();

    // ---- L2: per etype, g_t = h1 @ W2t ----
    short8 a2[4];
    #pragma unroll
    for (int ks = 0; ks < 4; ++ks)
        a2[ks] = *(const short8*)&s_h1[(w * 16 + lr) * 136 + ks * 32 + lg * 8];
    for (int t = gt0; t < gt1; ++t) {
        f32x4 acc2[4];
        #pragma unroll
        for (int nt = 0; nt < 4; ++nt) acc2[nt] = (f32x4){0.f, 0.f, 0.f, 0.f};
        #pragma unroll
        for (int nt = 0; nt < 4; ++nt) {
            #pragma unroll
            for (int ks = 0; ks < 4; ++ks) {
                short8 b = *(const short8*)&w2t[((size_t)t * OUT_DIM + nt * 16 + lr) * HID_DIM + ks * 32 + lg * 8];
                acc2[nt] = __builtin_amdgcn_mfma_f32_16x16x32_bf16(a2[ks], b, acc2[nt], 0, 0, 0);
            }
        }
        __syncthreads();          // prev s_out consumers done
        #pragma unroll
        for (int nt = 0; nt < 4; ++nt)
            #pragma unroll
            for (int r = 0; r < 4; ++r)
                s_out[(w * 16 + lg * 4 + r) * 72 + nt * 16 + lr] = f2bf(acc2[nt][r]);
        __syncthreads();
        size_t pb = (size_t)(t - gt0) * N_NODES;
        #pragma unroll
        for (int j = 0; j < 4; ++j) {
            int flat = j * 256 + tid;
            int rrow = flat >> 4, c4 = (flat & 15) * 4;
            int n = base + rrow;
            if (n < N_NODES)
                *(ushort4*)&g[(pb + n) * OUT_DIM + c4] = *(const ushort4*)&s_out[rrow * 72 + c4];
        }
    }
}

// ------ layer-2 gather: 16-lane group per node (4 nodes/wave); lane owns uint2 (4 bf16).
// ------ No cross-lane fold. kmax group-uniform => shfl always uniform.
__global__ __launch_bounds__(256) void k_gather2(const int* __restrict__ rowptr,
                                                 const int* __restrict__ csr,
                                                 const u32* __restrict__ g32,
                                                 u32* __restrict__ h232) {
    int tid = threadIdx.x;
    int fl = tid & 15;                        // uint2 index within 128B row
    int lanebase = tid & 48;                  // 16-lane group base within wave
    int n = blockIdx.x * 16 + (tid >> 4);     // 16 nodes per block
    int kb = n * N_ETYPES;
    float acc0 = 0.f, acc1 = 0.f, acc2 = 0.f, acc3 = 0.f;
    for (int tc = 0; tc < N_ETYPES; ++tc) {
        int rp0 = rowptr[kb + tc];
        int deg = rowptr[kb + tc + 1] - rp0;
        int stageA = csr[rp0 + fl];           // entries 0..15
        int stageB = csr[rp0 + 16 + fl];      // entries 16..31 (csr padded)
        int kmax = deg < 32 ? deg : 32;
        int kA = kmax < 16 ? kmax : 16;
        const u32* gp = g32 + (size_t)tc * N_NODES * 32;
        uint2 v = *(const uint2*)&gp[(size_t)n * 32 + fl * 2];    // self
        float s0 = lo2f(v.x), s1 = hi2f(v.x), s2 = lo2f(v.y), s3 = hi2f(v.y);
        float r0 = 0.f, r1 = 0.f, r2 = 0.f, r3 = 0.f;
        int k = 0;
        for (; k + 3 < kA; k += 4) {          // phase A: 4 rows in flight
            int p0 = __shfl(stageA, lanebase + k);
            int p1 = __shfl(stageA, lanebase + k + 1);
            int p2 = __shfl(stageA, lanebase + k + 2);
            int p3 = __shfl(stageA, lanebase + k + 3);
            uint2 v0 = *(const uint2*)&gp[(size_t)p0 * 32 + fl * 2];
            uint2 v1 = *(const uint2*)&gp[(size_t)p1 * 32 + fl * 2];
            uint2 v2 = *(const uint2*)&gp[(size_t)p2 * 32 + fl * 2];
            uint2 v3 = *(const uint2*)&gp[(size_t)p3 * 32 + fl * 2];
            s0 += lo2f(v0.x); s1 += hi2f(v0.x); s2 += lo2f(v0.y); s3 += hi2f(v0.y);
            r0 += lo2f(v1.x); r1 += hi2f(v1.x); r2 += lo2f(v1.y); r3 += hi2f(v1.y);
            s0 += lo2f(v2.x); s1 += hi2f(v2.x); s2 += lo2f(v2.y); s3 += hi2f(v2.y);
            r0 += lo2f(v3.x); r1 += hi2f(v3.x); r2 += lo2f(v3.y); r3 += hi2f(v3.y);
        }
        for (; k < kA; ++k) {
            int p0 = __shfl(stageA, lanebase + k);
            uint2 v0 = *(const uint2*)&gp[(size_t)p0 * 32 + fl * 2];
            s0 += lo2f(v0.x); s1 += hi2f(v0.x); s2 += lo2f(v0.y); s3 += hi2f(v0.y);
        }
        for (k = 16; k + 3 < kmax; k += 4) {  // phase B: entries 16..31
            int p0 = __shfl(stageB, lanebase + k - 16);
            int p1 = __shfl(stageB, lanebase + k - 15);
            int p2 = __shfl(stageB, lanebase + k - 14);
            int p3 = __shfl(stageB, lanebase + k - 13);
            uint2 v0 = *(const uint2*)&gp[(size_t)p0 * 32 + fl * 2];
            uint2 v1 = *(const uint2*)&gp[(size_t)p1 * 32 + fl * 2];
            uint2 v2 = *(const uint2*)&gp[(size_t)p2 * 32 + fl * 2];
            uint2 v3 = *(const uint2*)&gp[(size_t)p3 * 32 + fl * 2];
            s0 += lo2f(v0.x); s1 += hi2f(v0.x); s2 += lo2f(v0.y); s3 += hi2f(v0.y);
            r0 += lo2f(v1.x); r1 += hi2f(v1.x); r2 += lo2f(v1.y); r3 += hi2f(v1.y);
            s0 += lo2f(v2.x); s1 += hi2f(v2.x); s2 += lo2f(v2.y); s3 += hi2f(v2.y);
            r0 += lo2f(v3.x); r1 += hi2f(v3.x); r2 += lo2f(v3.y); r3 += hi2f(v3.y);
        }
        for (; k < kmax && k >= 16; ++k) {
            int p0 = __shfl(stageB, lanebase + k - 16);
            uint2 v0 = *(const uint2*)&gp[(size_t)p0 * 32 + fl * 2];
            s0 += lo2f(v0.x); s1 += hi2f(v0.x); s2 += lo2f(v0.y); s3 += hi2f(v0.y);
        }
        for (k = 32; k < deg; ++k) {          // deg>32: ~never; uniform broadcast loads
            int p0 = csr[rp0 + k];
            uint2 v0 = *(const uint2*)&gp[(size_t)p0 * 32 + fl * 2];
            s0 += lo2f(v0.x); s1 += hi2f(v0.x); s2 += lo2f(v0.y); s3 += hi2f(v0.y);
        }
        float inv = 1.0f / (float)(deg + 1);
        acc0 = fmaf(s0 + r0, inv, acc0);
        acc1 = fmaf(s1 + r1, inv, acc1);
        acc2 = fmaf(s2 + r2, inv, acc2);
        acc3 = fmaf(s3 + r3, inv, acc3);
    }
    uint2 o;
    o.x = (u32)f2bf(acc0) | ((u32)f2bf(acc1) << 16);
    o.y = (u32)f2bf(acc2) | ((u32)f2bf(acc3) << 16);
    *(uint2*)&h232[(size_t)n * 32 + fl * 2] = o;
}

// ---------------- pooling stage 1: chunked partial sums (sorted gids -> few atomics) -------
__global__ __launch_bounds__(256) void k_pool1(const u16* __restrict__ h2,
                                               const int* __restrict__ gids,
                                               float* __restrict__ out_acc) {
    int w = threadIdx.x >> 6, lane = threadIdx.x & 63;
    int n0 = blockIdx.x * 256 + w * 64;
    int nend = n0 + 64; if (nend > N_NODES) nend = N_NODES;
    float acc = 0.f;
    int cur = -1;
    for (int n = n0; n < nend; ++n) {
        int gid = gids[n];
        if (gid != cur) {
            if (cur >= 0) atomicAdd(&out_acc[cur * OUT_DIM + lane], acc);
            acc = 0.f; cur = gid;
        }
        acc += bf2f(h2[(size_t)n * OUT_DIM + lane]);
    }
    if (cur >= 0) atomicAdd(&out_acc[cur * OUT_DIM + lane], acc);
}

// ---------------- pooling stage 2: divide by count, add bias ----------------
__global__ __launch_bounds__(64) void k_pool2(const float* __restrict__ out_acc,
                                              const int* __restrict__ gids,
                                              const float* __restrict__ b2,
                                              float* __restrict__ out) {
    int gid = blockIdx.x, j = threadIdx.x;
    int lo = 0, hi = N_NODES;
    while (lo < hi) { int mid = (lo + hi) >> 1; if (gids[mid] < gid) lo = mid + 1; else hi = mid; }
    int start = lo;
    hi = N_NODES;
    while (lo < hi) { int mid = (lo + hi) >> 1; if (gids[mid] < gid + 1) lo = mid + 1; else hi = mid; }
    int count = lo - start;
    float b = 0.f;
    #pragma unroll
    for (int t = 0; t < N_ETYPES; ++t) b += b2[t * OUT_DIM + j];
    float c = (float)count;
    out[gid * OUT_DIM + j] = (out_acc[gid * OUT_DIM + j] + c * b) / fmaxf(c, 1.0f);
}

extern "C" void kernel_launch(void* const* d_in, const int* in_sizes, int n_in,
                              void* d_out, int out_size, void* d_ws, size_t ws_size,
                              hipStream_t stream) {
    const float* x    = (const float*)d_in[0];
    const int*   edges= (const int*)d_in[1];
    const int*   gids = (const int*)d_in[2];
    const float* W1   = (const float*)d_in[3];
    const float* b1   = (const float*)d_in[4];
    const float* W2   = (const float*)d_in[5];
    const float* b2   = (const float*)d_in[6];
    float* out = (float*)d_out;

    // word-offset (u32) workspace layout; total 31,335,296 words = 125.3 MB (audited r10)
    int*   bin_cnt = (int*)d_ws;                          // 0       (256)
    int*   rowptr  = bin_cnt + 256;                       // 256     (500,016)
    int*   csr     = bin_cnt + 500272;                    // 500,272 (4,000,080)
    u16*   xb      = (u16*)(bin_cnt + 4500352);           // 4,500,352 (1,600,000 u16 = 800,000 w)
    u16*   w1t     = (u16*)(bin_cnt + 6100352);           // 6,100,352 (20,480 u16 = 10,240 w)
    u16*   w2t     = (u16*)(bin_cnt + 6110592);           // 6,110,592 (40,960 u16 = 20,480 w)
    float* b1s     = (float*)(bin_cnt + 6131072);         // 6,131,072 (128, pad to 6,131,200)
    u16*   acat    = (u16*)(bin_cnt + 6131200);           // 6,131,200 (12,000,000 u16 = 6,000,000 w)
    u16*   g       = (u16*)(bin_cnt + 12131200);          // 12,131,200 (32,000,000 u16 = 16,000,000 w)
    int*   binned  = bin_cnt + 12131200;                  // alias over g head (4,515,840 w)
    u16*   h2      = (u16*)(bin_cnt + 28131200);          // 28,131,200 (6,400,000 u16 = 3,200,000 w)
    float* out_acc = (float*)(bin_cnt + 31331200);        // 31,331,200 (4,096)

    hipMemsetAsync(bin_cnt, 0, 256 * sizeof(int), stream);
    hipMemsetAsync(out_acc, 0, NUM_GRAPHS * OUT_DIM * sizeof(float), stream);

    k_bin<<<BIN_BLOCKS + PREP_BLOCKS, 256, 0, stream>>>(
        edges, bin_cnt, binned, W1, W2, b1, x, w1t, w2t, b1s, xb);
    k_csr<<<NBINS, 256, 0, stream>>>(bin_cnt, binned, rowptr, csr);

    k_gather1<<<dim3(N_NODES / 32, N_ETYPES), 256, 0, stream>>>(
        rowptr, csr, (const u32*)xb, (u32*)acat);

    int nblk = (N_NODES + 63) / 64;
    k_gemm12<<<nblk, 256, 0, stream>>>(acat, w1t, w2t, b1s, g, 0, 5);   // single pass, 5 planes
    k_gather2<<<N_NODES / 16, 256, 0, stream>>>(rowptr, csr, (const u32*)g, (u32*)h2);

    k_pool1<<<(N_NODES + 255) / 256, 256, 0, stream>>>(h2, gids, out_acc);
    k_pool2<<<NUM_GRAPHS, 64, 0, stream>>>(out_acc, gids, b2, out);
}

// Round 15
// 402.979 us; speedup vs baseline: 1.0663x; 1.0663x over previous
//
#include <hip/hip_runtime.h>

#define N_NODES 100000
#define N_EDGES 800000
#define N_ETYPES 5
#define NUM_GRAPHS 64
#define IN_DIM 23
#define HID_DIM 128
#define OUT_DIM 64
#define N_KEYS (N_NODES * N_ETYPES)      // 500,000  (key = dst*5 + t)
#define KPB 2048                         // keys per bin
#define NBINS ((N_KEYS + KPB - 1) / KPB) // 245
#define BIN_CAP 18432                    // Poisson(16384) + 16 sigma
#define CHUNK 8192                       // edges per k_bin block
#define TOT_EDGES (N_EDGES * N_ETYPES)   // 4,000,000

typedef unsigned short u16;
typedef unsigned int u32;
using short8 = __attribute__((ext_vector_type(8))) short;
using f32x4  = __attribute__((ext_vector_type(4))) float;

__device__ __forceinline__ float bf2f(u16 v) {
    union { unsigned u; float f; } x; x.u = ((unsigned)v) << 16; return x.f;
}
__device__ __forceinline__ float lo2f(u32 v) {
    union { unsigned u; float f; } x; x.u = v << 16; return x.f;
}
__device__ __forceinline__ float hi2f(u32 v) {
    union { unsigned u; float f; } x; x.u = v & 0xffff0000u; return x.f;
}
__device__ __forceinline__ u16 f2bf(float f) {
    union { float f; unsigned u; } x; x.f = f;
    unsigned r = x.u + 0x7fff + ((x.u >> 16) & 1);   // RNE
    return (u16)(r >> 16);
}

// ---------------- prep: W1t/W2t/b1s (bf16, transposed, zero-padded) + xb ----------------
__global__ __launch_bounds__(256) void k_prep(const float* __restrict__ W1,
                                              const float* __restrict__ W2,
                                              const float* __restrict__ b1,
                                              const float* __restrict__ x,
                                              u16* __restrict__ w1t,
                                              u16* __restrict__ w2t,
                                              float* __restrict__ b1s,
                                              u16* __restrict__ xb) {
    int stride = gridDim.x * 256;
    int g0 = blockIdx.x * 256 + threadIdx.x;
    for (int i = g0; i < HID_DIM * 160; i += stride) {       // w1t[hid][k], k=t*32+f
        int hid = i / 160, k = i - hid * 160;
        int t = k >> 5, f = k & 31;
        w1t[i] = (f < IN_DIM) ? f2bf(W1[((size_t)t * IN_DIM + f) * HID_DIM + hid]) : (u16)0;
    }
    for (int i = g0; i < N_ETYPES * OUT_DIM * HID_DIM; i += stride) { // w2t[t][out][k]
        int t = i >> 13, r = i & 8191;
        int out = r >> 7, k = r & 127;
        w2t[i] = f2bf(W2[((size_t)t * HID_DIM + k) * OUT_DIM + out]);
    }
    for (int i = g0; i < HID_DIM; i += stride) {
        float s = 0.f;
        #pragma unroll
        for (int t = 0; t < N_ETYPES; ++t) s += b1[t * HID_DIM + i];
        b1s[i] = s;
    }
    for (int i = g0; i < N_NODES * 32; i += stride) {        // xb padded to 32 cols
        int n = i >> 5, f = i & 31;
        xb[i] = (f < IN_DIM) ? f2bf(x[(size_t)n * IN_DIM + f]) : (u16)0;
    }
}

// ------- pass A: bin edges by key>>11; per-wave LDS histograms, 8 KB LDS total -------
// ------- (s_key stash removed: sweep 2 re-reads dst and recomputes the key) -------
__global__ __launch_bounds__(256) void k_bin(const int* __restrict__ edges,
                                             int* __restrict__ bin_cnt,
                                             int* __restrict__ binned) {
    __shared__ int s_hist[4][256];    // 4 KB (per-wave)
    __shared__ int s_base[4][256];    // 4 KB (per-wave running offsets)
    int tid = threadIdx.x;
    int w = tid >> 6;
    int g0 = blockIdx.x * CHUNK;
    int nch = TOT_EDGES - g0; if (nch > CHUNK) nch = CHUNK;
    for (int i = tid; i < 4 * 256; i += 256) ((int*)s_hist)[i] = 0;
    __syncthreads();
    // sweep 1: read dst, per-wave histogram
    for (int i = tid; i < nch; i += 256) {
        int gi = g0 + i;
        int t = (unsigned)gi / (unsigned)N_EDGES;          // const divisor -> magic mul
        int e = gi - t * N_EDGES;
        int dst = edges[((size_t)t * 2 + 1) * N_EDGES + e];
        atomicAdd(&s_hist[w][(dst * N_ETYPES + t) >> 11], 1);
    }
    __syncthreads();
    // reserve: one global atomic per non-empty (block, bin); per-wave sub-bases
    for (int i = tid; i < NBINS; i += 256) {
        int h0 = s_hist[0][i], h1 = s_hist[1][i], h2 = s_hist[2][i], h3 = s_hist[3][i];
        int h = h0 + h1 + h2 + h3;
        int base = h ? atomicAdd(&bin_cnt[i], h) : 0;
        s_base[0][i] = base;
        s_base[1][i] = base + h0;
        s_base[2][i] = base + h0 + h1;
        s_base[3][i] = base + h0 + h1 + h2;
    }
    __syncthreads();
    // sweep 2: re-read dst (recompute key) + src, place entries
    for (int i = tid; i < nch; i += 256) {
        int gi = g0 + i;
        int t = (unsigned)gi / (unsigned)N_EDGES;
        int e = gi - t * N_EDGES;
        int dst = edges[((size_t)t * 2 + 1) * N_EDGES + e];
        int src = edges[((size_t)t * 2 + 0) * N_EDGES + e];
        int key = dst * N_ETYPES + t;
        int bin = key >> 11;
        int pos = atomicAdd(&s_base[w][bin], 1);
        if (pos < BIN_CAP)
            binned[(size_t)bin * BIN_CAP + pos] = ((key & 2047) << 17) | src;
    }
}

// ---------------- pass B: per-bin counting sort -> rowptr + CSR ----------------
__global__ __launch_bounds__(256) void k_csr(const int* __restrict__ bin_cnt,
                                             const int* __restrict__ binned,
                                             int* __restrict__ rowptr,
                                             int* __restrict__ csr) {
    __shared__ int s_cnt[KPB];        // 8 KB
    __shared__ int s_ofs[KPB];        // 8 KB
    __shared__ int s_red[256];
    int tid = threadIdx.x;
    int b = blockIdx.x;
    // csr_base = sum bin_cnt[0..b)
    int ps = 0;
    for (int i = tid; i < b; i += 256) ps += bin_cnt[i];
    s_red[tid] = ps;
    __syncthreads();
    for (int s = 128; s > 0; s >>= 1) {
        if (tid < s) s_red[tid] += s_red[tid + s];
        __syncthreads();
    }
    int csr_base = s_red[0];
    __syncthreads();
    int cnt_b = bin_cnt[b];
    if (cnt_b > BIN_CAP) cnt_b = BIN_CAP;
    int key0 = b * KPB;
    int keys_in = N_KEYS - key0; if (keys_in > KPB) keys_in = KPB;
    for (int i = tid; i < KPB; i += 256) s_cnt[i] = 0;
    __syncthreads();
    const int* ep = binned + (size_t)b * BIN_CAP;
    for (int i = tid; i < cnt_b; i += 256)
        atomicAdd(&s_cnt[ep[i] >> 17], 1);
    __syncthreads();
    // exclusive scan over 2048 counters: 8/thread serial + block Hillis-Steele
    int loc[8]; int base_t = 0;
    #pragma unroll
    for (int q = 0; q < 8; ++q) { loc[q] = base_t; base_t += s_cnt[tid * 8 + q]; }
    s_red[tid] = base_t;
    __syncthreads();
    for (int s = 1; s < 256; s <<= 1) {
        int add = (tid >= s) ? s_red[tid - s] : 0;
        __syncthreads();
        s_red[tid] += add;
        __syncthreads();
    }
    int excl = (tid == 0) ? 0 : s_red[tid - 1];
    #pragma unroll
    for (int q = 0; q < 8; ++q) {
        int k = tid * 8 + q;
        int o = excl + loc[q];
        s_ofs[k] = o;
        if (k < keys_in) rowptr[key0 + k] = csr_base + o;
    }
    if (b == NBINS - 1 && tid == 0) rowptr[N_KEYS] = csr_base + cnt_b;
    __syncthreads();
    // scatter into CSR (writes land in a 64KB L2-hot window)
    for (int i = tid; i < cnt_b; i += 256) {
        int entry = ep[i];
        int pos = atomicAdd(&s_ofs[entry >> 17], 1);
        csr[csr_base + pos] = entry & 0x1FFFF;
    }
}

// ------ layer-1 gather: 8-lane group per (node,etype); lane owns uint2 (4 bf16 cols).
// ------ No cross-lane fold needed. kmax group-uniform => shfl always uniform.
__global__ __launch_bounds__(256) void k_gather1(const int* __restrict__ rowptr,
                                                 const int* __restrict__ csr,
                                                 const u32* __restrict__ xb32,
                                                 u32* __restrict__ acat32) {
    int tid = threadIdx.x;
    int fl = tid & 7;                         // uint2 index within 64B row
    int lanebase = tid & 56;                  // 8-lane group base within wave
    int n = blockIdx.x * 32 + (tid >> 3);     // 32 nodes per block
    int t = blockIdx.y;
    int key = n * N_ETYPES + t;
    int rp0 = rowptr[key];
    int deg = rowptr[key + 1] - rp0;
    int stageA = csr[rp0 + fl];               // entries 0..7
    int stageB = csr[rp0 + 8 + fl];           // entries 8..15 (csr padded)
    int kmax = deg < 16 ? deg : 16;
    int kA = kmax < 8 ? kmax : 8;
    uint2 v = *(const uint2*)&xb32[(size_t)n * 16 + fl * 2];   // self (pad cols zero)
    float a0 = lo2f(v.x), a1 = hi2f(v.x), a2 = lo2f(v.y), a3 = hi2f(v.y);
    float b0 = 0.f, b1v = 0.f, b2 = 0.f, b3 = 0.f;
    int k = 0;
    for (; k + 3 < kA; k += 4) {              // phase A: 4 rows in flight
        int s0 = __shfl(stageA, lanebase + k);
        int s1 = __shfl(stageA, lanebase + k + 1);
        int s2 = __shfl(stageA, lanebase + k + 2);
        int s3 = __shfl(stageA, lanebase + k + 3);
        uint2 v0 = *(const uint2*)&xb32[(size_t)s0 * 16 + fl * 2];
        uint2 v1 = *(const uint2*)&xb32[(size_t)s1 * 16 + fl * 2];
        uint2 v2 = *(const uint2*)&xb32[(size_t)s2 * 16 + fl * 2];
        uint2 v3 = *(const uint2*)&xb32[(size_t)s3 * 16 + fl * 2];
        a0 += lo2f(v0.x); a1 += hi2f(v0.x); a2 += lo2f(v0.y); a3 += hi2f(v0.y);
        b0 += lo2f(v1.x); b1v += hi2f(v1.x); b2 += lo2f(v1.y); b3 += hi2f(v1.y);
        a0 += lo2f(v2.x); a1 += hi2f(v2.x); a2 += lo2f(v2.y); a3 += hi2f(v2.y);
        b0 += lo2f(v3.x); b1v += hi2f(v3.x); b2 += lo2f(v3.y); b3 += hi2f(v3.y);
    }
    for (; k < kA; ++k) {
        int s0 = __shfl(stageA, lanebase + k);
        uint2 v0 = *(const uint2*)&xb32[(size_t)s0 * 16 + fl * 2];
        a0 += lo2f(v0.x); a1 += hi2f(v0.x); a2 += lo2f(v0.y); a3 += hi2f(v0.y);
    }
    for (k = 8; k + 3 < kmax; k += 4) {       // phase B: entries 8..15
        int s0 = __shfl(stageB, lanebase + k - 8);
        int s1 = __shfl(stageB, lanebase + k - 7);
        int s2 = __shfl(stageB, lanebase + k - 6);
        int s3 = __shfl(stageB, lanebase + k - 5);
        uint2 v0 = *(const uint2*)&xb32[(size_t)s0 * 16 + fl * 2];
        uint2 v1 = *(const uint2*)&xb32[(size_t)s1 * 16 + fl * 2];
        uint2 v2 = *(const uint2*)&xb32[(size_t)s2 * 16 + fl * 2];
        uint2 v3 = *(const uint2*)&xb32[(size_t)s3 * 16 + fl * 2];
        a0 += lo2f(v0.x); a1 += hi2f(v0.x); a2 += lo2f(v0.y); a3 += hi2f(v0.y);
        b0 += lo2f(v1.x); b1v += hi2f(v1.x); b2 += lo2f(v1.y); b3 += hi2f(v1.y);
        a0 += lo2f(v2.x); a1 += hi2f(v2.x); a2 += lo2f(v2.y); a3 += hi2f(v2.y);
        b0 += lo2f(v3.x); b1v += hi2f(v3.x); b2 += lo2f(v3.y); b3 += hi2f(v3.y);
    }
    for (; k < kmax && k >= 8; ++k) {
        int s0 = __shfl(stageB, lanebase + k - 8);
        uint2 v0 = *(const uint2*)&xb32[(size_t)s0 * 16 + fl * 2];
        a0 += lo2f(v0.x); a1 += hi2f(v0.x); a2 += lo2f(v0.y); a3 += hi2f(v0.y);
    }
    for (k = 16; k < deg; ++k) {              // deg>16: rare; uniform broadcast loads
        int s0 = csr[rp0 + k];
        uint2 v0 = *(const uint2*)&xb32[(size_t)s0 * 16 + fl * 2];
        a0 += lo2f(v0.x); a1 += hi2f(v0.x); a2 += lo2f(v0.y); a3 += hi2f(v0.y);
    }
    a0 += b0; a1 += b1v; a2 += b2; a3 += b3;
    if (fl < 6) {
        float inv = 1.0f / (float)(deg + 1);
        uint2 o;
        o.x = (u32)f2bf(a0 * inv) | ((u32)f2bf(a1 * inv) << 16);
        o.y = (u32)f2bf(a2 * inv) | ((u32)f2bf(a3 * inv) << 16);
        *(uint2*)&acat32[(size_t)n * 60 + t * 12 + fl * 2] = o;
    }
}

// ---------------- fused GEMM chain: acat -> MFMA L1+relu (LDS) -> MFMA L2 -> g -------------
__global__ __launch_bounds__(256) void k_gemm12(const u16* __restrict__ acat,
                                                const u16* __restrict__ w1t,
                                                const u16* __restrict__ w2t,
                                                const float* __restrict__ b1s,
                                                u16* __restrict__ g,
                                                int gt0, int gt1) {
    __shared__ u16 s_a[64 * 168];     // [64][160+8]  21504 B  (reused as s_out)
    __shared__ u16 s_h1[64 * 136];    // [64][128+8]  17408 B
    u16* s_out = s_a;                 // dead after A-frags are in registers
    int tid = threadIdx.x;
    int base = blockIdx.x * 64;

    // stage acat tile: expand [120] packed -> [160] zero-padded (coalesced ushort4)
    for (int i = tid; i < 64 * 40; i += 256) {
        int r = i / 40, col4 = i - r * 40;
        int t = col4 >> 3, q4 = col4 & 7;
        ushort4 v = {0, 0, 0, 0};
        if (q4 < 6 && base + r < N_NODES)
            v = *(const ushort4*)&acat[(size_t)(base + r) * 120 + t * 24 + q4 * 4];
        *(ushort4*)&s_a[r * 168 + t * 32 + q4 * 4] = v;
    }
    __syncthreads();

    int l = tid & 63, w = tid >> 6;
    int lr = l & 15, lg = l >> 4;

    // ---- L1: h1 = relu(s_a @ W1t + b1s) ----
    short8 a5[5];
    #pragma unroll
    for (int ks = 0; ks < 5; ++ks)
        a5[ks] = *(const short8*)&s_a[(w * 16 + lr) * 168 + ks * 32 + lg * 8];
    {
        f32x4 acc[8];
        #pragma unroll
        for (int nt = 0; nt < 8; ++nt) acc[nt] = (f32x4){0.f, 0.f, 0.f, 0.f};
        #pragma unroll
        for (int nt = 0; nt < 8; ++nt) {
            #pragma unroll
            for (int ks = 0; ks < 5; ++ks) {
                short8 b = *(const short8*)&w1t[(nt * 16 + lr) * 160 + ks * 32 + lg * 8];
                acc[nt] = __builtin_amdgcn_mfma_f32_16x16x32_bf16(a5[ks], b, acc[nt], 0, 0, 0);
            }
        }
        #pragma unroll
        for (int nt = 0; nt < 8; ++nt) {
            float bias = b1s[nt * 16 + lr];
            #pragma unroll
            for (int r = 0; r < 4; ++r) {
                float h = acc[nt][r] + bias;
                s_h1[(w * 16 + lg * 4 + r) * 136 + nt * 16 + lr] = f2bf(h > 0.f ? h : 0.f);
            }
        }
    }
    __syncthreads();

    // ---- L2: per etype, g_t = h1 @ W2t ----
    short8 a2[4];
    #pragma unroll
    for (int ks = 0; ks < 4; ++ks)
        a2[ks] = *(const short8*)&s_h1[(w * 16 + lr) * 136 + ks * 32 + lg * 8];
    for (int t = gt0; t < gt1; ++t) {
        f32x4 acc2[4];
        #pragma unroll
        for (int nt = 0; nt < 4; ++nt) acc2[nt] = (f32x4){0.f, 0.f, 0.f, 0.f};
        #pragma unroll
        for (int nt = 0; nt < 4; ++nt) {
            #pragma unroll
            for (int ks = 0; ks < 4; ++ks) {
                short8 b = *(const short8*)&w2t[((size_t)t * OUT_DIM + nt * 16 + lr) * HID_DIM + ks * 32 + lg * 8];
                acc2[nt] = __builtin_amdgcn_mfma_f32_16x16x32_bf16(a2[ks], b, acc2[nt], 0, 0, 0);
            }
        }
        __syncthreads();          // prev s_out consumers done
        #pragma unroll
        for (int nt = 0; nt < 4; ++nt)
            #pragma unroll
            for (int r = 0; r < 4; ++r)
                s_out[(w * 16 + lg * 4 + r) * 72 + nt * 16 + lr] = f2bf(acc2[nt][r]);
        __syncthreads();
        size_t pb = (size_t)(t - gt0) * N_NODES;
        #pragma unroll
        for (int j = 0; j < 4; ++j) {
            int flat = j * 256 + tid;
            int rrow = flat >> 4, c4 = (flat & 15) * 4;
            int n = base + rrow;
            if (n < N_NODES)
                *(ushort4*)&g[(pb + n) * OUT_DIM + c4] = *(const ushort4*)&s_out[rrow * 72 + c4];
        }
    }
}

// ------ layer-2 gather: 16-lane group per node (4 nodes/wave); lane owns uint2 (4 bf16).
// ------ No cross-lane fold. kmax group-uniform => shfl always uniform.
__global__ __launch_bounds__(256) void k_gather2(const int* __restrict__ rowptr,
                                                 const int* __restrict__ csr,
                                                 const u32* __restrict__ g32,
                                                 u32* __restrict__ h232) {
    int tid = threadIdx.x;
    int fl = tid & 15;                        // uint2 index within 128B row
    int lanebase = tid & 48;                  // 16-lane group base within wave
    int n = blockIdx.x * 16 + (tid >> 4);     // 16 nodes per block
    int kb = n * N_ETYPES;
    float acc0 = 0.f, acc1 = 0.f, acc2 = 0.f, acc3 = 0.f;
    for (int tc = 0; tc < N_ETYPES; ++tc) {
        int rp0 = rowptr[kb + tc];
        int deg = rowptr[kb + tc + 1] - rp0;
        int stageA = csr[rp0 + fl];           // entries 0..15
        int stageB = csr[rp0 + 16 + fl];      // entries 16..31 (csr padded)
        int kmax = deg < 32 ? deg : 32;
        int kA = kmax < 16 ? kmax : 16;
        const u32* gp = g32 + (size_t)tc * N_NODES * 32;
        uint2 v = *(const uint2*)&gp[(size_t)n * 32 + fl * 2];    // self
        float s0 = lo2f(v.x), s1 = hi2f(v.x), s2 = lo2f(v.y), s3 = hi2f(v.y);
        float r0 = 0.f, r1 = 0.f, r2 = 0.f, r3 = 0.f;
        int k = 0;
        for (; k + 3 < kA; k += 4) {          // phase A: 4 rows in flight
            int p0 = __shfl(stageA, lanebase + k);
            int p1 = __shfl(stageA, lanebase + k + 1);
            int p2 = __shfl(stageA, lanebase + k + 2);
            int p3 = __shfl(stageA, lanebase + k + 3);
            uint2 v0 = *(const uint2*)&gp[(size_t)p0 * 32 + fl * 2];
            uint2 v1 = *(const uint2*)&gp[(size_t)p1 * 32 + fl * 2];
            uint2 v2 = *(const uint2*)&gp[(size_t)p2 * 32 + fl * 2];
            uint2 v3 = *(const uint2*)&gp[(size_t)p3 * 32 + fl * 2];
            s0 += lo2f(v0.x); s1 += hi2f(v0.x); s2 += lo2f(v0.y); s3 += hi2f(v0.y);
            r0 += lo2f(v1.x); r1 += hi2f(v1.x); r2 += lo2f(v1.y); r3 += hi2f(v1.y);
            s0 += lo2f(v2.x); s1 += hi2f(v2.x); s2 += lo2f(v2.y); s3 += hi2f(v2.y);
            r0 += lo2f(v3.x); r1 += hi2f(v3.x); r2 += lo2f(v3.y); r3 += hi2f(v3.y);
        }
        for (; k < kA; ++k) {
            int p0 = __shfl(stageA, lanebase + k);
            uint2 v0 = *(const uint2*)&gp[(size_t)p0 * 32 + fl * 2];
            s0 += lo2f(v0.x); s1 += hi2f(v0.x); s2 += lo2f(v0.y); s3 += hi2f(v0.y);
        }
        for (k = 16; k + 3 < kmax; k += 4) {  // phase B: entries 16..31
            int p0 = __shfl(stageB, lanebase + k - 16);
            int p1 = __shfl(stageB, lanebase + k - 15);
            int p2 = __shfl(stageB, lanebase + k - 14);
            int p3 = __shfl(stageB, lanebase + k - 13);
            uint2 v0 = *(const uint2*)&gp[(size_t)p0 * 32 + fl * 2];
            uint2 v1 = *(const uint2*)&gp[(size_t)p1 * 32 + fl * 2];
            uint2 v2 = *(const uint2*)&gp[(size_t)p2 * 32 + fl * 2];
            uint2 v3 = *(const uint2*)&gp[(size_t)p3 * 32 + fl * 2];
            s0 += lo2f(v0.x); s1 += hi2f(v0.x); s2 += lo2f(v0.y); s3 += hi2f(v0.y);
            r0 += lo2f(v1.x); r1 += hi2f(v1.x); r2 += lo2f(v1.y); r3 += hi2f(v1.y);
            s0 += lo2f(v2.x); s1 += hi2f(v2.x); s2 += lo2f(v2.y); s3 += hi2f(v2.y);
            r0 += lo2f(v3.x); r1 += hi2f(v3.x); r2 += lo2f(v3.y); r3 += hi2f(v3.y);
        }
        for (; k < kmax && k >= 16; ++k) {
            int p0 = __shfl(stageB, lanebase + k - 16);
            uint2 v0 = *(const uint2*)&gp[(size_t)p0 * 32 + fl * 2];
            s0 += lo2f(v0.x); s1 += hi2f(v0.x); s2 += lo2f(v0.y); s3 += hi2f(v0.y);
        }
        for (k = 32; k < deg; ++k) {          // deg>32: ~never; uniform broadcast loads
            int p0 = csr[rp0 + k];
            uint2 v0 = *(const uint2*)&gp[(size_t)p0 * 32 + fl * 2];
            s0 += lo2f(v0.x); s1 += hi2f(v0.x); s2 += lo2f(v0.y); s3 += hi2f(v0.y);
        }
        float inv = 1.0f / (float)(deg + 1);
        acc0 = fmaf(s0 + r0, inv, acc0);
        acc1 = fmaf(s1 + r1, inv, acc1);
        acc2 = fmaf(s2 + r2, inv, acc2);
        acc3 = fmaf(s3 + r3, inv, acc3);
    }
    uint2 o;
    o.x = (u32)f2bf(acc0) | ((u32)f2bf(acc1) << 16);
    o.y = (u32)f2bf(acc2) | ((u32)f2bf(acc3) << 16);
    *(uint2*)&h232[(size_t)n * 32 + fl * 2] = o;
}

// ---------------- pooling stage 1: chunked partial sums (sorted gids -> few atomics) -------
__global__ __launch_bounds__(256) void k_pool1(const u16* __restrict__ h2,
                                               const int* __restrict__ gids,
                                               float* __restrict__ out_acc) {
    int w = threadIdx.x >> 6, lane = threadIdx.x & 63;
    int n0 = blockIdx.x * 256 + w * 64;
    int nend = n0 + 64; if (nend > N_NODES) nend = N_NODES;
    float acc = 0.f;
    int cur = -1;
    for (int n = n0; n < nend; ++n) {
        int gid = gids[n];
        if (gid != cur) {
            if (cur >= 0) atomicAdd(&out_acc[cur * OUT_DIM + lane], acc);
            acc = 0.f; cur = gid;
        }
        acc += bf2f(h2[(size_t)n * OUT_DIM + lane]);
    }
    if (cur >= 0) atomicAdd(&out_acc[cur * OUT_DIM + lane], acc);
}

// ---------------- pooling stage 2: divide by count, add bias ----------------
__global__ __launch_bounds__(64) void k_pool2(const float* __restrict__ out_acc,
                                              const int* __restrict__ gids,
                                              const float* __restrict__ b2,
                                              float* __restrict__ out) {
    int gid = blockIdx.x, j = threadIdx.x;
    int lo = 0, hi = N_NODES;
    while (lo < hi) { int mid = (lo + hi) >> 1; if (gids[mid] < gid) lo = mid + 1; else hi = mid; }
    int start = lo;
    hi = N_NODES;
    while (lo < hi) { int mid = (lo + hi) >> 1; if (gids[mid] < gid + 1) lo = mid + 1; else hi = mid; }
    int count = lo - start;
    float b = 0.f;
    #pragma unroll
    for (int t = 0; t < N_ETYPES; ++t) b += b2[t * OUT_DIM + j];
    float c = (float)count;
    out[gid * OUT_DIM + j] = (out_acc[gid * OUT_DIM + j] + c * b) / fmaxf(c, 1.0f);
}

extern "C" void kernel_launch(void* const* d_in, const int* in_sizes, int n_in,
                              void* d_out, int out_size, void* d_ws, size_t ws_size,
                              hipStream_t stream) {
    const float* x    = (const float*)d_in[0];
    const int*   edges= (const int*)d_in[1];
    const int*   gids = (const int*)d_in[2];
    const float* W1   = (const float*)d_in[3];
    const float* b1   = (const float*)d_in[4];
    const float* W2   = (const float*)d_in[5];
    const float* b2   = (const float*)d_in[6];
    float* out = (float*)d_out;

    // word-offset (u32) workspace layout; total 31,335,296 words = 125.3 MB (audited r10)
    int*   bin_cnt = (int*)d_ws;                          // 0       (256)
    int*   rowptr  = bin_cnt + 256;                       // 256     (500,016)
    int*   csr     = bin_cnt + 500272;                    // 500,272 (4,000,080)
    u16*   xb      = (u16*)(bin_cnt + 4500352);           // 4,500,352 (1,600,000 u16 = 800,000 w)
    u16*   w1t     = (u16*)(bin_cnt + 6100352);           // 6,100,352 (20,480 u16 = 10,240 w)
    u16*   w2t     = (u16*)(bin_cnt + 6110592);           // 6,110,592 (40,960 u16 = 20,480 w)
    float* b1s     = (float*)(bin_cnt + 6131072);         // 6,131,072 (128, pad to 6,131,200)
    u16*   acat    = (u16*)(bin_cnt + 6131200);           // 6,131,200 (12,000,000 u16 = 6,000,000 w)
    u16*   g       = (u16*)(bin_cnt + 12131200);          // 12,131,200 (32,000,000 u16 = 16,000,000 w)
    int*   binned  = bin_cnt + 12131200;                  // alias over g head (4,515,840 w)
    u16*   h2      = (u16*)(bin_cnt + 28131200);          // 28,131,200 (6,400,000 u16 = 3,200,000 w)
    float* out_acc = (float*)(bin_cnt + 31331200);        // 31,331,200 (4,096)

    hipMemsetAsync(bin_cnt, 0, 256 * sizeof(int), stream);
    hipMemsetAsync(out_acc, 0, NUM_GRAPHS * OUT_DIM * sizeof(float), stream);

    k_prep<<<1024, 256, 0, stream>>>(W1, W2, b1, x, w1t, w2t, b1s, xb);
    k_bin<<<(TOT_EDGES + CHUNK - 1) / CHUNK, 256, 0, stream>>>(edges, bin_cnt, binned);
    k_csr<<<NBINS, 256, 0, stream>>>(bin_cnt, binned, rowptr, csr);

    k_gather1<<<dim3(N_NODES / 32, N_ETYPES), 256, 0, stream>>>(
        rowptr, csr, (const u32*)xb, (u32*)acat);

    int nblk = (N_NODES + 63) / 64;
    k_gemm12<<<nblk, 256, 0, stream>>>(acat, w1t, w2t, b1s, g, 0, 5);   // single pass, 5 planes
    k_gather2<<<N_NODES / 16, 256, 0, stream>>>(rowptr, csr, (const u32*)g, (u32*)h2);

    k_pool1<<<(N_NODES + 255) / 256, 256, 0, stream>>>(h2, gids, out_acc);
    k_pool2<<<NUM_GRAPHS, 64, 0, stream>>>(out_acc, gids, b2, out);
}

// Round 16
// 399.677 us; speedup vs baseline: 1.0751x; 1.0083x over previous
//
#include <hip/hip_runtime.h>

#define N_NODES 100000
#define N_EDGES 800000
#define N_ETYPES 5
#define NUM_GRAPHS 64
#define IN_DIM 23
#define HID_DIM 128
#define OUT_DIM 64
#define N_KEYS (N_NODES * N_ETYPES)      // 500,000  (key = dst*5 + t)
#define KPB 2048                         // keys per bin
#define NBINS ((N_KEYS + KPB - 1) / KPB) // 245
#define BIN_CAP 18432                    // Poisson(16384) + 16 sigma
#define CHUNK 8192                       // edges per k_bin block
#define TOT_EDGES (N_EDGES * N_ETYPES)   // 4,000,000

typedef unsigned short u16;
typedef unsigned int u32;
using short8 = __attribute__((ext_vector_type(8))) short;
using f32x4  = __attribute__((ext_vector_type(4))) float;

__device__ __forceinline__ float bf2f(u16 v) {
    union { unsigned u; float f; } x; x.u = ((unsigned)v) << 16; return x.f;
}
__device__ __forceinline__ float lo2f(u32 v) {
    union { unsigned u; float f; } x; x.u = v << 16; return x.f;
}
__device__ __forceinline__ float hi2f(u32 v) {
    union { unsigned u; float f; } x; x.u = v & 0xffff0000u; return x.f;
}
__device__ __forceinline__ u16 f2bf(float f) {
    union { float f; unsigned u; } x; x.f = f;
    unsigned r = x.u + 0x7fff + ((x.u >> 16) & 1);   // RNE
    return (u16)(r >> 16);
}
__device__ __forceinline__ void lds_fence() {
    asm volatile("s_waitcnt lgkmcnt(0)" ::: "memory");
}

// ---------------- prep: W1t/W2t/b1s (bf16, transposed, zero-padded) + xb ----------------
__global__ __launch_bounds__(256) void k_prep(const float* __restrict__ W1,
                                              const float* __restrict__ W2,
                                              const float* __restrict__ b1,
                                              const float* __restrict__ x,
                                              u16* __restrict__ w1t,
                                              u16* __restrict__ w2t,
                                              float* __restrict__ b1s,
                                              u16* __restrict__ xb) {
    int stride = gridDim.x * 256;
    int g0 = blockIdx.x * 256 + threadIdx.x;
    for (int i = g0; i < HID_DIM * 160; i += stride) {       // w1t[hid][k], k=t*32+f
        int hid = i / 160, k = i - hid * 160;
        int t = k >> 5, f = k & 31;
        w1t[i] = (f < IN_DIM) ? f2bf(W1[((size_t)t * IN_DIM + f) * HID_DIM + hid]) : (u16)0;
    }
    for (int i = g0; i < N_ETYPES * OUT_DIM * HID_DIM; i += stride) { // w2t[t][out][k]
        int t = i >> 13, r = i & 8191;
        int out = r >> 7, k = r & 127;
        w2t[i] = f2bf(W2[((size_t)t * HID_DIM + k) * OUT_DIM + out]);
    }
    for (int i = g0; i < HID_DIM; i += stride) {
        float s = 0.f;
        #pragma unroll
        for (int t = 0; t < N_ETYPES; ++t) s += b1[t * HID_DIM + i];
        b1s[i] = s;
    }
    for (int i = g0; i < N_NODES * 32; i += stride) {        // xb padded to 32 cols
        int n = i >> 5, f = i & 31;
        xb[i] = (f < IN_DIM) ? f2bf(x[(size_t)n * IN_DIM + f]) : (u16)0;
    }
}

// ------- pass A: bin edges by key>>11; per-wave LDS histograms, 8 KB LDS total -------
__global__ __launch_bounds__(256) void k_bin(const int* __restrict__ edges,
                                             int* __restrict__ bin_cnt,
                                             int* __restrict__ binned) {
    __shared__ int s_hist[4][256];    // 4 KB (per-wave)
    __shared__ int s_base[4][256];    // 4 KB (per-wave running offsets)
    int tid = threadIdx.x;
    int w = tid >> 6;
    int g0 = blockIdx.x * CHUNK;
    int nch = TOT_EDGES - g0; if (nch > CHUNK) nch = CHUNK;
    for (int i = tid; i < 4 * 256; i += 256) ((int*)s_hist)[i] = 0;
    __syncthreads();
    // sweep 1: read dst, per-wave histogram
    for (int i = tid; i < nch; i += 256) {
        int gi = g0 + i;
        int t = (unsigned)gi / (unsigned)N_EDGES;          // const divisor -> magic mul
        int e = gi - t * N_EDGES;
        int dst = edges[((size_t)t * 2 + 1) * N_EDGES + e];
        atomicAdd(&s_hist[w][(dst * N_ETYPES + t) >> 11], 1);
    }
    __syncthreads();
    // reserve: one global atomic per non-empty (block, bin); per-wave sub-bases
    for (int i = tid; i < NBINS; i += 256) {
        int h0 = s_hist[0][i], h1 = s_hist[1][i], h2 = s_hist[2][i], h3 = s_hist[3][i];
        int h = h0 + h1 + h2 + h3;
        int base = h ? atomicAdd(&bin_cnt[i], h) : 0;
        s_base[0][i] = base;
        s_base[1][i] = base + h0;
        s_base[2][i] = base + h0 + h1;
        s_base[3][i] = base + h0 + h1 + h2;
    }
    __syncthreads();
    // sweep 2: re-read dst (recompute key) + src, place entries
    for (int i = tid; i < nch; i += 256) {
        int gi = g0 + i;
        int t = (unsigned)gi / (unsigned)N_EDGES;
        int e = gi - t * N_EDGES;
        int dst = edges[((size_t)t * 2 + 1) * N_EDGES + e];
        int src = edges[((size_t)t * 2 + 0) * N_EDGES + e];
        int key = dst * N_ETYPES + t;
        int bin = key >> 11;
        int pos = atomicAdd(&s_base[w][bin], 1);
        if (pos < BIN_CAP)
            binned[(size_t)bin * BIN_CAP + pos] = ((key & 2047) << 17) | src;
    }
}

// ---------------- pass B: per-bin counting sort -> rowptr + CSR ----------------
__global__ __launch_bounds__(256) void k_csr(const int* __restrict__ bin_cnt,
                                             const int* __restrict__ binned,
                                             int* __restrict__ rowptr,
                                             int* __restrict__ csr) {
    __shared__ int s_cnt[KPB];        // 8 KB
    __shared__ int s_ofs[KPB];        // 8 KB
    __shared__ int s_red[256];
    int tid = threadIdx.x;
    int b = blockIdx.x;
    // csr_base = sum bin_cnt[0..b)
    int ps = 0;
    for (int i = tid; i < b; i += 256) ps += bin_cnt[i];
    s_red[tid] = ps;
    __syncthreads();
    for (int s = 128; s > 0; s >>= 1) {
        if (tid < s) s_red[tid] += s_red[tid + s];
        __syncthreads();
    }
    int csr_base = s_red[0];
    __syncthreads();
    int cnt_b = bin_cnt[b];
    if (cnt_b > BIN_CAP) cnt_b = BIN_CAP;
    int key0 = b * KPB;
    int keys_in = N_KEYS - key0; if (keys_in > KPB) keys_in = KPB;
    for (int i = tid; i < KPB; i += 256) s_cnt[i] = 0;
    __syncthreads();
    const int* ep = binned + (size_t)b * BIN_CAP;
    for (int i = tid; i < cnt_b; i += 256)
        atomicAdd(&s_cnt[ep[i] >> 17], 1);
    __syncthreads();
    // exclusive scan over 2048 counters: 8/thread serial + block Hillis-Steele
    int loc[8]; int base_t = 0;
    #pragma unroll
    for (int q = 0; q < 8; ++q) { loc[q] = base_t; base_t += s_cnt[tid * 8 + q]; }
    s_red[tid] = base_t;
    __syncthreads();
    for (int s = 1; s < 256; s <<= 1) {
        int add = (tid >= s) ? s_red[tid - s] : 0;
        __syncthreads();
        s_red[tid] += add;
        __syncthreads();
    }
    int excl = (tid == 0) ? 0 : s_red[tid - 1];
    #pragma unroll
    for (int q = 0; q < 8; ++q) {
        int k = tid * 8 + q;
        int o = excl + loc[q];
        s_ofs[k] = o;
        if (k < keys_in) rowptr[key0 + k] = csr_base + o;
    }
    if (b == NBINS - 1 && tid == 0) rowptr[N_KEYS] = csr_base + cnt_b;
    __syncthreads();
    // scatter into CSR (writes land in a 64KB L2-hot window)
    for (int i = tid; i < cnt_b; i += 256) {
        int entry = ep[i];
        int pos = atomicAdd(&s_ofs[entry >> 17], 1);
        csr[csr_base + pos] = entry & 0x1FFFF;
    }
}

// ------ layer-1 gather: 8-lane group per (node,etype); lane owns uint2 (4 bf16 cols).
__global__ __launch_bounds__(256) void k_gather1(const int* __restrict__ rowptr,
                                                 const int* __restrict__ csr,
                                                 const u32* __restrict__ xb32,
                                                 u32* __restrict__ acat32) {
    int tid = threadIdx.x;
    int fl = tid & 7;                         // uint2 index within 64B row
    int lanebase = tid & 56;                  // 8-lane group base within wave
    int n = blockIdx.x * 32 + (tid >> 3);     // 32 nodes per block
    int t = blockIdx.y;
    int key = n * N_ETYPES + t;
    int rp0 = rowptr[key];
    int deg = rowptr[key + 1] - rp0;
    int stageA = csr[rp0 + fl];               // entries 0..7
    int stageB = csr[rp0 + 8 + fl];           // entries 8..15 (csr padded)
    int kmax = deg < 16 ? deg : 16;
    int kA = kmax < 8 ? kmax : 8;
    uint2 v = *(const uint2*)&xb32[(size_t)n * 16 + fl * 2];   // self (pad cols zero)
    float a0 = lo2f(v.x), a1 = hi2f(v.x), a2 = lo2f(v.y), a3 = hi2f(v.y);
    float b0 = 0.f, b1v = 0.f, b2 = 0.f, b3 = 0.f;
    int k = 0;
    for (; k + 3 < kA; k += 4) {              // phase A: 4 rows in flight
        int s0 = __shfl(stageA, lanebase + k);
        int s1 = __shfl(stageA, lanebase + k + 1);
        int s2 = __shfl(stageA, lanebase + k + 2);
        int s3 = __shfl(stageA, lanebase + k + 3);
        uint2 v0 = *(const uint2*)&xb32[(size_t)s0 * 16 + fl * 2];
        uint2 v1 = *(const uint2*)&xb32[(size_t)s1 * 16 + fl * 2];
        uint2 v2 = *(const uint2*)&xb32[(size_t)s2 * 16 + fl * 2];
        uint2 v3 = *(const uint2*)&xb32[(size_t)s3 * 16 + fl * 2];
        a0 += lo2f(v0.x); a1 += hi2f(v0.x); a2 += lo2f(v0.y); a3 += hi2f(v0.y);
        b0 += lo2f(v1.x); b1v += hi2f(v1.x); b2 += lo2f(v1.y); b3 += hi2f(v1.y);
        a0 += lo2f(v2.x); a1 += hi2f(v2.x); a2 += lo2f(v2.y); a3 += hi2f(v2.y);
        b0 += lo2f(v3.x); b1v += hi2f(v3.x); b2 += lo2f(v3.y); b3 += hi2f(v3.y);
    }
    for (; k < kA; ++k) {
        int s0 = __shfl(stageA, lanebase + k);
        uint2 v0 = *(const uint2*)&xb32[(size_t)s0 * 16 + fl * 2];
        a0 += lo2f(v0.x); a1 += hi2f(v0.x); a2 += lo2f(v0.y); a3 += hi2f(v0.y);
    }
    for (k = 8; k + 3 < kmax; k += 4) {       // phase B: entries 8..15
        int s0 = __shfl(stageB, lanebase + k - 8);
        int s1 = __shfl(stageB, lanebase + k - 7);
        int s2 = __shfl(stageB, lanebase + k - 6);
        int s3 = __shfl(stageB, lanebase + k - 5);
        uint2 v0 = *(const uint2*)&xb32[(size_t)s0 * 16 + fl * 2];
        uint2 v1 = *(const uint2*)&xb32[(size_t)s1 * 16 + fl * 2];
        uint2 v2 = *(const uint2*)&xb32[(size_t)s2 * 16 + fl * 2];
        uint2 v3 = *(const uint2*)&xb32[(size_t)s3 * 16 + fl * 2];
        a0 += lo2f(v0.x); a1 += hi2f(v0.x); a2 += lo2f(v0.y); a3 += hi2f(v0.y);
        b0 += lo2f(v1.x); b1v += hi2f(v1.x); b2 += lo2f(v1.y); b3 += hi2f(v1.y);
        a0 += lo2f(v2.x); a1 += hi2f(v2.x); a2 += lo2f(v2.y); a3 += hi2f(v2.y);
        b0 += lo2f(v3.x); b1v += hi2f(v3.x); b2 += lo2f(v3.y); b3 += hi2f(v3.y);
    }
    for (; k < kmax && k >= 8; ++k) {
        int s0 = __shfl(stageB, lanebase + k - 8);
        uint2 v0 = *(const uint2*)&xb32[(size_t)s0 * 16 + fl * 2];
        a0 += lo2f(v0.x); a1 += hi2f(v0.x); a2 += lo2f(v0.y); a3 += hi2f(v0.y);
    }
    for (k = 16; k < deg; ++k) {              // deg>16: rare; uniform broadcast loads
        int s0 = csr[rp0 + k];
        uint2 v0 = *(const uint2*)&xb32[(size_t)s0 * 16 + fl * 2];
        a0 += lo2f(v0.x); a1 += hi2f(v0.x); a2 += lo2f(v0.y); a3 += hi2f(v0.y);
    }
    a0 += b0; a1 += b1v; a2 += b2; a3 += b3;
    if (fl < 6) {
        float inv = 1.0f / (float)(deg + 1);
        uint2 o;
        o.x = (u32)f2bf(a0 * inv) | ((u32)f2bf(a1 * inv) << 16);
        o.y = (u32)f2bf(a2 * inv) | ((u32)f2bf(a3 * inv) << 16);
        *(uint2*)&acat32[(size_t)n * 60 + t * 12 + fl * 2] = o;
    }
}

// ------ fused GEMM chain, BARRIER-FREE: one wave owns 16 nodes end-to-end. ------
// ------ A-frags direct from global acat (lg=3 k-slice is the zero pad, matching
// ------ w1t's zero rows); h1/out live in per-wave LDS slices; ordering via lgkmcnt.
__global__ __launch_bounds__(256) void k_gemm12(const u16* __restrict__ acat,
                                                const u16* __restrict__ w1t,
                                                const u16* __restrict__ w2t,
                                                const float* __restrict__ b1s,
                                                u16* __restrict__ g) {
    __shared__ u16 s_h1[4][16 * 136];   // per-wave 4352 B  (total 17408)
    __shared__ u16 s_out[4][16 * 72];   // per-wave 2304 B  (total 9216)
    int tid = threadIdx.x;
    int w = tid >> 6, l = tid & 63;
    int lr = l & 15, lg = l >> 4;
    int base = blockIdx.x * 64 + w * 16;         // 16 nodes per wave
    int nrow = base + lr;
    size_t arow = (size_t)(nrow < N_NODES ? nrow : 0) * 120;

    // ---- L1: A-frags straight from acat; k-slice lg=3 (cols 24..31) is zero ----
    short8 a5[5];
    #pragma unroll
    for (int ks = 0; ks < 5; ++ks) {
        short8 av = (short8){0, 0, 0, 0, 0, 0, 0, 0};
        if (lg < 3) av = *(const short8*)&acat[arow + ks * 24 + lg * 8];
        a5[ks] = av;
    }
    {
        f32x4 acc[8];
        #pragma unroll
        for (int nt = 0; nt < 8; ++nt) acc[nt] = (f32x4){0.f, 0.f, 0.f, 0.f};
        #pragma unroll
        for (int nt = 0; nt < 8; ++nt) {
            #pragma unroll
            for (int ks = 0; ks < 5; ++ks) {
                short8 b = *(const short8*)&w1t[(nt * 16 + lr) * 160 + ks * 32 + lg * 8];
                acc[nt] = __builtin_amdgcn_mfma_f32_16x16x32_bf16(a5[ks], b, acc[nt], 0, 0, 0);
            }
        }
        #pragma unroll
        for (int nt = 0; nt < 8; ++nt) {
            float bias = b1s[nt * 16 + lr];
            #pragma unroll
            for (int r = 0; r < 4; ++r) {
                float h = acc[nt][r] + bias;
                s_h1[w][(lg * 4 + r) * 136 + nt * 16 + lr] = f2bf(h > 0.f ? h : 0.f);
            }
        }
    }
    lds_fence();                                  // same-wave h1 write -> read

    // ---- L2: per etype, g_t = h1 @ W2t ----
    short8 a2[4];
    #pragma unroll
    for (int ks = 0; ks < 4; ++ks)
        a2[ks] = *(const short8*)&s_h1[w][lr * 136 + ks * 32 + lg * 8];
    for (int t = 0; t < N_ETYPES; ++t) {
        f32x4 acc2[4];
        #pragma unroll
        for (int nt = 0; nt < 4; ++nt) acc2[nt] = (f32x4){0.f, 0.f, 0.f, 0.f};
        #pragma unroll
        for (int nt = 0; nt < 4; ++nt) {
            #pragma unroll
            for (int ks = 0; ks < 4; ++ks) {
                short8 b = *(const short8*)&w2t[((size_t)t * OUT_DIM + nt * 16 + lr) * HID_DIM + ks * 32 + lg * 8];
                acc2[nt] = __builtin_amdgcn_mfma_f32_16x16x32_bf16(a2[ks], b, acc2[nt], 0, 0, 0);
            }
        }
        lds_fence();                              // prev iteration's s_out reads done
        #pragma unroll
        for (int nt = 0; nt < 4; ++nt)
            #pragma unroll
            for (int r = 0; r < 4; ++r)
                s_out[w][(lg * 4 + r) * 72 + nt * 16 + lr] = f2bf(acc2[nt][r]);
        lds_fence();                              // s_out writes visible to this wave
        size_t pb = (size_t)t * N_NODES;
        #pragma unroll
        for (int j = 0; j < 4; ++j) {
            int i = j * 64 + l;                   // 256 ushort4 chunks = 16 rows x 64 cols
            int row = i >> 4, c4 = (i & 15) * 4;
            int n = base + row;
            if (n < N_NODES)
                *(ushort4*)&g[(pb + n) * OUT_DIM + c4] = *(const ushort4*)&s_out[w][row * 72 + c4];
        }
    }
}

// ------ layer-2 gather: 16-lane group per node (4 nodes/wave); lane owns uint2 (4 bf16).
__global__ __launch_bounds__(256) void k_gather2(const int* __restrict__ rowptr,
                                                 const int* __restrict__ csr,
                                                 const u32* __restrict__ g32,
                                                 u32* __restrict__ h232) {
    int tid = threadIdx.x;
    int fl = tid & 15;                        // uint2 index within 128B row
    int lanebase = tid & 48;                  // 16-lane group base within wave
    int n = blockIdx.x * 16 + (tid >> 4);     // 16 nodes per block
    int kb = n * N_ETYPES;
    float acc0 = 0.f, acc1 = 0.f, acc2 = 0.f, acc3 = 0.f;
    for (int tc = 0; tc < N_ETYPES; ++tc) {
        int rp0 = rowptr[kb + tc];
        int deg = rowptr[kb + tc + 1] - rp0;
        int stageA = csr[rp0 + fl];           // entries 0..15
        int stageB = csr[rp0 + 16 + fl];      // entries 16..31 (csr padded)
        int kmax = deg < 32 ? deg : 32;
        int kA = kmax < 16 ? kmax : 16;
        const u32* gp = g32 + (size_t)tc * N_NODES * 32;
        uint2 v = *(const uint2*)&gp[(size_t)n * 32 + fl * 2];    // self
        float s0 = lo2f(v.x), s1 = hi2f(v.x), s2 = lo2f(v.y), s3 = hi2f(v.y);
        float r0 = 0.f, r1 = 0.f, r2 = 0.f, r3 = 0.f;
        int k = 0;
        for (; k + 3 < kA; k += 4) {          // phase A: 4 rows in flight
            int p0 = __shfl(stageA, lanebase + k);
            int p1 = __shfl(stageA, lanebase + k + 1);
            int p2 = __shfl(stageA, lanebase + k + 2);
            int p3 = __shfl(stageA, lanebase + k + 3);
            uint2 v0 = *(const uint2*)&gp[(size_t)p0 * 32 + fl * 2];
            uint2 v1 = *(const uint2*)&gp[(size_t)p1 * 32 + fl * 2];
            uint2 v2 = *(const uint2*)&gp[(size_t)p2 * 32 + fl * 2];
            uint2 v3 = *(const uint2*)&gp[(size_t)p3 * 32 + fl * 2];
            s0 += lo2f(v0.x); s1 += hi2f(v0.x); s2 += lo2f(v0.y); s3 += hi2f(v0.y);
            r0 += lo2f(v1.x); r1 += hi2f(v1.x); r2 += lo2f(v1.y); r3 += hi2f(v1.y);
            s0 += lo2f(v2.x); s1 += hi2f(v2.x); s2 += lo2f(v2.y); s3 += hi2f(v2.y);
            r0 += lo2f(v3.x); r1 += hi2f(v3.x); r2 += lo2f(v3.y); r3 += hi2f(v3.y);
        }
        for (; k < kA; ++k) {
            int p0 = __shfl(stageA, lanebase + k);
            uint2 v0 = *(const uint2*)&gp[(size_t)p0 * 32 + fl * 2];
            s0 += lo2f(v0.x); s1 += hi2f(v0.x); s2 += lo2f(v0.y); s3 += hi2f(v0.y);
        }
        for (k = 16; k + 3 < kmax; k += 4) {  // phase B: entries 16..31
            int p0 = __shfl(stageB, lanebase + k - 16);
            int p1 = __shfl(stageB, lanebase + k - 15);
            int p2 = __shfl(stageB, lanebase + k - 14);
            int p3 = __shfl(stageB, lanebase + k - 13);
            uint2 v0 = *(const uint2*)&gp[(size_t)p0 * 32 + fl * 2];
            uint2 v1 = *(const uint2*)&gp[(size_t)p1 * 32 + fl * 2];
            uint2 v2 = *(const uint2*)&gp[(size_t)p2 * 32 + fl * 2];
            uint2 v3 = *(const uint2*)&gp[(size_t)p3 * 32 + fl * 2];
            s0 += lo2f(v0.x); s1 += hi2f(v0.x); s2 += lo2f(v0.y); s3 += hi2f(v0.y);
            r0 += lo2f(v1.x); r1 += hi2f(v1.x); r2 += lo2f(v1.y); r3 += hi2f(v1.y);
            s0 += lo2f(v2.x); s1 += hi2f(v2.x); s2 += lo2f(v2.y); s3 += hi2f(v2.y);
            r0 += lo2f(v3.x); r1 += hi2f(v3.x); r2 += lo2f(v3.y); r3 += hi2f(v3.y);
        }
        for (; k < kmax && k >= 16; ++k) {
            int p0 = __shfl(stageB, lanebase + k - 16);
            uint2 v0 = *(const uint2*)&gp[(size_t)p0 * 32 + fl * 2];
            s0 += lo2f(v0.x); s1 += hi2f(v0.x); s2 += lo2f(v0.y); s3 += hi2f(v0.y);
        }
        for (k = 32; k < deg; ++k) {          // deg>32: ~never; uniform broadcast loads
            int p0 = csr[rp0 + k];
            uint2 v0 = *(const uint2*)&gp[(size_t)p0 * 32 + fl * 2];
            s0 += lo2f(v0.x); s1 += hi2f(v0.x); s2 += lo2f(v0.y); s3 += hi2f(v0.y);
        }
        float inv = 1.0f / (float)(deg + 1);
        acc0 = fmaf(s0 + r0, inv, acc0);
        acc1 = fmaf(s1 + r1, inv, acc1);
        acc2 = fmaf(s2 + r2, inv, acc2);
        acc3 = fmaf(s3 + r3, inv, acc3);
    }
    uint2 o;
    o.x = (u32)f2bf(acc0) | ((u32)f2bf(acc1) << 16);
    o.y = (u32)f2bf(acc2) | ((u32)f2bf(acc3) << 16);
    *(uint2*)&h232[(size_t)n * 32 + fl * 2] = o;
}

// ---------------- pooling stage 1: chunked partial sums (sorted gids -> few atomics) -------
__global__ __launch_bounds__(256) void k_pool1(const u16* __restrict__ h2,
                                               const int* __restrict__ gids,
                                               float* __restrict__ out_acc) {
    int w = threadIdx.x >> 6, lane = threadIdx.x & 63;
    int n0 = blockIdx.x * 256 + w * 64;
    int nend = n0 + 64; if (nend > N_NODES) nend = N_NODES;
    float acc = 0.f;
    int cur = -1;
    for (int n = n0; n < nend; ++n) {
        int gid = gids[n];
        if (gid != cur) {
            if (cur >= 0) atomicAdd(&out_acc[cur * OUT_DIM + lane], acc);
            acc = 0.f; cur = gid;
        }
        acc += bf2f(h2[(size_t)n * OUT_DIM + lane]);
    }
    if (cur >= 0) atomicAdd(&out_acc[cur * OUT_DIM + lane], acc);
}

// ---------------- pooling stage 2: divide by count, add bias ----------------
__global__ __launch_bounds__(64) void k_pool2(const float* __restrict__ out_acc,
                                              const int* __restrict__ gids,
                                              const float* __restrict__ b2,
                                              float* __restrict__ out) {
    int gid = blockIdx.x, j = threadIdx.x;
    int lo = 0, hi = N_NODES;
    while (lo < hi) { int mid = (lo + hi) >> 1; if (gids[mid] < gid) lo = mid + 1; else hi = mid; }
    int start = lo;
    hi = N_NODES;
    while (lo < hi) { int mid = (lo + hi) >> 1; if (gids[mid] < gid + 1) lo = mid + 1; else hi = mid; }
    int count = lo - start;
    float b = 0.f;
    #pragma unroll
    for (int t = 0; t < N_ETYPES; ++t) b += b2[t * OUT_DIM + j];
    float c = (float)count;
    out[gid * OUT_DIM + j] = (out_acc[gid * OUT_DIM + j] + c * b) / fmaxf(c, 1.0f);
}

extern "C" void kernel_launch(void* const* d_in, const int* in_sizes, int n_in,
                              void* d_out, int out_size, void* d_ws, size_t ws_size,
                              hipStream_t stream) {
    const float* x    = (const float*)d_in[0];
    const int*   edges= (const int*)d_in[1];
    const int*   gids = (const int*)d_in[2];
    const float* W1   = (const float*)d_in[3];
    const float* b1   = (const float*)d_in[4];
    const float* W2   = (const float*)d_in[5];
    const float* b2   = (const float*)d_in[6];
    float* out = (float*)d_out;

    // word-offset (u32) workspace layout; total 31,335,296 words = 125.3 MB (audited r10)
    int*   bin_cnt = (int*)d_ws;                          // 0       (256)
    int*   rowptr  = bin_cnt + 256;                       // 256     (500,016)
    int*   csr     = bin_cnt + 500272;                    // 500,272 (4,000,080)
    u16*   xb      = (u16*)(bin_cnt + 4500352);           // 4,500,352 (1,600,000 u16 = 800,000 w)
    u16*   w1t     = (u16*)(bin_cnt + 6100352);           // 6,100,352 (20,480 u16 = 10,240 w)
    u16*   w2t     = (u16*)(bin_cnt + 6110592);           // 6,110,592 (40,960 u16 = 20,480 w)
    float* b1s     = (float*)(bin_cnt + 6131072);         // 6,131,072 (128, pad to 6,131,200)
    u16*   acat    = (u16*)(bin_cnt + 6131200);           // 6,131,200 (12,000,000 u16 = 6,000,000 w)
    u16*   g       = (u16*)(bin_cnt + 12131200);          // 12,131,200 (32,000,000 u16 = 16,000,000 w)
    int*   binned  = bin_cnt + 12131200;                  // alias over g head (4,515,840 w)
    u16*   h2      = (u16*)(bin_cnt + 28131200);          // 28,131,200 (6,400,000 u16 = 3,200,000 w)
    float* out_acc = (float*)(bin_cnt + 31331200);        // 31,331,200 (4,096)

    hipMemsetAsync(bin_cnt, 0, 256 * sizeof(int), stream);
    hipMemsetAsync(out_acc, 0, NUM_GRAPHS * OUT_DIM * sizeof(float), stream);

    k_prep<<<1024, 256, 0, stream>>>(W1, W2, b1, x, w1t, w2t, b1s, xb);
    k_bin<<<(TOT_EDGES + CHUNK - 1) / CHUNK, 256, 0, stream>>>(edges, bin_cnt, binned);
    k_csr<<<NBINS, 256, 0, stream>>>(bin_cnt, binned, rowptr, csr);

    k_gather1<<<dim3(N_NODES / 32, N_ETYPES), 256, 0, stream>>>(
        rowptr, csr, (const u32*)xb, (u32*)acat);

    int nblk = (N_NODES + 63) / 64;
    k_gemm12<<<nblk, 256, 0, stream>>>(acat, w1t, w2t, b1s, g);
    k_gather2<<<N_NODES / 16, 256, 0, stream>>>(rowptr, csr, (const u32*)g, (u32*)h2);

    k_pool1<<<(N_NODES + 255) / 256, 256, 0, stream>>>(h2, gids, out_acc);
    k_pool2<<<NUM_GRAPHS, 64, 0, stream>>>(out_acc, gids, b2, out);
}

// Round 17
// 397.214 us; speedup vs baseline: 1.0818x; 1.0062x over previous
//
#include <hip/hip_runtime.h>

#define N_NODES 100000
#define N_EDGES 800000
#define N_ETYPES 5
#define NUM_GRAPHS 64
#define IN_DIM 23
#define HID_DIM 128
#define OUT_DIM 64
#define N_KEYS (N_NODES * N_ETYPES)      // 500,000  (key = dst*5 + t)
#define KPB 2048                         // keys per bin
#define NBINS ((N_KEYS + KPB - 1) / KPB) // 245
#define BIN_CAP 18432                    // Poisson(16384) + 16 sigma
#define CHUNK 8192                       // edges per k_bin block
#define TOT_EDGES (N_EDGES * N_ETYPES)   // 4,000,000

typedef unsigned short u16;
typedef unsigned int u32;
using short8 = __attribute__((ext_vector_type(8))) short;
using f32x4  = __attribute__((ext_vector_type(4))) float;

__device__ __forceinline__ float bf2f(u16 v) {
    union { unsigned u; float f; } x; x.u = ((unsigned)v) << 16; return x.f;
}
__device__ __forceinline__ float lo2f(u32 v) {
    union { unsigned u; float f; } x; x.u = v << 16; return x.f;
}
__device__ __forceinline__ float hi2f(u32 v) {
    union { unsigned u; float f; } x; x.u = v & 0xffff0000u; return x.f;
}
__device__ __forceinline__ u16 f2bf(float f) {
    union { float f; unsigned u; } x; x.f = f;
    unsigned r = x.u + 0x7fff + ((x.u >> 16) & 1);   // RNE
    return (u16)(r >> 16);
}
__device__ __forceinline__ void lds_fence() {
    asm volatile("s_waitcnt lgkmcnt(0)" ::: "memory");
}

// ---------------- prep: W1t/W2t/b1s (bf16, transposed, zero-padded) + xb ----------------
__global__ __launch_bounds__(256) void k_prep(const float* __restrict__ W1,
                                              const float* __restrict__ W2,
                                              const float* __restrict__ b1,
                                              const float* __restrict__ x,
                                              u16* __restrict__ w1t,
                                              u16* __restrict__ w2t,
                                              float* __restrict__ b1s,
                                              u16* __restrict__ xb) {
    int stride = gridDim.x * 256;
    int g0 = blockIdx.x * 256 + threadIdx.x;
    for (int i = g0; i < HID_DIM * 160; i += stride) {       // w1t[hid][k], k=t*32+f
        int hid = i / 160, k = i - hid * 160;
        int t = k >> 5, f = k & 31;
        w1t[i] = (f < IN_DIM) ? f2bf(W1[((size_t)t * IN_DIM + f) * HID_DIM + hid]) : (u16)0;
    }
    for (int i = g0; i < N_ETYPES * OUT_DIM * HID_DIM; i += stride) { // w2t[t][out][k]
        int t = i >> 13, r = i & 8191;
        int out = r >> 7, k = r & 127;
        w2t[i] = f2bf(W2[((size_t)t * HID_DIM + k) * OUT_DIM + out]);
    }
    for (int i = g0; i < HID_DIM; i += stride) {
        float s = 0.f;
        #pragma unroll
        for (int t = 0; t < N_ETYPES; ++t) s += b1[t * HID_DIM + i];
        b1s[i] = s;
    }
    for (int i = g0; i < N_NODES * 32; i += stride) {        // xb padded to 32 cols
        int n = i >> 5, f = i & 31;
        xb[i] = (f < IN_DIM) ? f2bf(x[(size_t)n * IN_DIM + f]) : (u16)0;
    }
}

// ------- pass A: bin edges by key>>11; per-wave LDS histograms, 8 KB LDS total -------
__global__ __launch_bounds__(256) void k_bin(const int* __restrict__ edges,
                                             int* __restrict__ bin_cnt,
                                             int* __restrict__ binned) {
    __shared__ int s_hist[4][256];    // 4 KB (per-wave)
    __shared__ int s_base[4][256];    // 4 KB (per-wave running offsets)
    int tid = threadIdx.x;
    int w = tid >> 6;
    int g0 = blockIdx.x * CHUNK;
    int nch = TOT_EDGES - g0; if (nch > CHUNK) nch = CHUNK;
    for (int i = tid; i < 4 * 256; i += 256) ((int*)s_hist)[i] = 0;
    __syncthreads();
    // sweep 1: read dst, per-wave histogram
    for (int i = tid; i < nch; i += 256) {
        int gi = g0 + i;
        int t = (unsigned)gi / (unsigned)N_EDGES;          // const divisor -> magic mul
        int e = gi - t * N_EDGES;
        int dst = edges[((size_t)t * 2 + 1) * N_EDGES + e];
        atomicAdd(&s_hist[w][(dst * N_ETYPES + t) >> 11], 1);
    }
    __syncthreads();
    // reserve: one global atomic per non-empty (block, bin); per-wave sub-bases
    for (int i = tid; i < NBINS; i += 256) {
        int h0 = s_hist[0][i], h1 = s_hist[1][i], h2 = s_hist[2][i], h3 = s_hist[3][i];
        int h = h0 + h1 + h2 + h3;
        int base = h ? atomicAdd(&bin_cnt[i], h) : 0;
        s_base[0][i] = base;
        s_base[1][i] = base + h0;
        s_base[2][i] = base + h0 + h1;
        s_base[3][i] = base + h0 + h1 + h2;
    }
    __syncthreads();
    // sweep 2: re-read dst (recompute key) + src, place entries
    for (int i = tid; i < nch; i += 256) {
        int gi = g0 + i;
        int t = (unsigned)gi / (unsigned)N_EDGES;
        int e = gi - t * N_EDGES;
        int dst = edges[((size_t)t * 2 + 1) * N_EDGES + e];
        int src = edges[((size_t)t * 2 + 0) * N_EDGES + e];
        int key = dst * N_ETYPES + t;
        int bin = key >> 11;
        int pos = atomicAdd(&s_base[w][bin], 1);
        if (pos < BIN_CAP)
            binned[(size_t)bin * BIN_CAP + pos] = ((key & 2047) << 17) | src;
    }
}

// ---------------- pass B: per-bin counting sort -> rowptr + CSR ----------------
__global__ __launch_bounds__(256) void k_csr(const int* __restrict__ bin_cnt,
                                             const int* __restrict__ binned,
                                             int* __restrict__ rowptr,
                                             int* __restrict__ csr) {
    __shared__ int s_cnt[KPB];        // 8 KB
    __shared__ int s_ofs[KPB];        // 8 KB
    __shared__ int s_red[256];
    int tid = threadIdx.x;
    int b = blockIdx.x;
    // csr_base = sum bin_cnt[0..b)
    int ps = 0;
    for (int i = tid; i < b; i += 256) ps += bin_cnt[i];
    s_red[tid] = ps;
    __syncthreads();
    for (int s = 128; s > 0; s >>= 1) {
        if (tid < s) s_red[tid] += s_red[tid + s];
        __syncthreads();
    }
    int csr_base = s_red[0];
    __syncthreads();
    int cnt_b = bin_cnt[b];
    if (cnt_b > BIN_CAP) cnt_b = BIN_CAP;
    int key0 = b * KPB;
    int keys_in = N_KEYS - key0; if (keys_in > KPB) keys_in = KPB;
    for (int i = tid; i < KPB; i += 256) s_cnt[i] = 0;
    __syncthreads();
    const int* ep = binned + (size_t)b * BIN_CAP;
    for (int i = tid; i < cnt_b; i += 256)
        atomicAdd(&s_cnt[ep[i] >> 17], 1);
    __syncthreads();
    // exclusive scan over 2048 counters: 8/thread serial + block Hillis-Steele
    int loc[8]; int base_t = 0;
    #pragma unroll
    for (int q = 0; q < 8; ++q) { loc[q] = base_t; base_t += s_cnt[tid * 8 + q]; }
    s_red[tid] = base_t;
    __syncthreads();
    for (int s = 1; s < 256; s <<= 1) {
        int add = (tid >= s) ? s_red[tid - s] : 0;
        __syncthreads();
        s_red[tid] += add;
        __syncthreads();
    }
    int excl = (tid == 0) ? 0 : s_red[tid - 1];
    #pragma unroll
    for (int q = 0; q < 8; ++q) {
        int k = tid * 8 + q;
        int o = excl + loc[q];
        s_ofs[k] = o;
        if (k < keys_in) rowptr[key0 + k] = csr_base + o;
    }
    if (b == NBINS - 1 && tid == 0) rowptr[N_KEYS] = csr_base + cnt_b;
    __syncthreads();
    // scatter into CSR (writes land in a 64KB L2-hot window)
    for (int i = tid; i < cnt_b; i += 256) {
        int entry = ep[i];
        int pos = atomicAdd(&s_ofs[entry >> 17], 1);
        csr[csr_base + pos] = entry & 0x1FFFF;
    }
}

// ------ layer-1 gather: 8-lane group per (node,etype); lane owns uint2 (4 bf16 cols).
// ------ 8-deep phase-A unroll; all loop bounds group-uniform -> shfl always uniform.
__global__ __launch_bounds__(256) void k_gather1(const int* __restrict__ rowptr,
                                                 const int* __restrict__ csr,
                                                 const u32* __restrict__ xb32,
                                                 u32* __restrict__ acat32) {
    int tid = threadIdx.x;
    int fl = tid & 7;                         // uint2 index within 64B row
    int lanebase = tid & 56;                  // 8-lane group base within wave
    int n = blockIdx.x * 32 + (tid >> 3);     // 32 nodes per block
    int t = blockIdx.y;
    int key = n * N_ETYPES + t;
    int rp0 = rowptr[key];
    int deg = rowptr[key + 1] - rp0;
    int kmax = deg < 16 ? deg : 16;
    int kA = kmax < 8 ? kmax : 8;
    int stageA = csr[rp0 + fl];               // entries 0..7
    int stageB = (kmax > 8) ? csr[rp0 + 8 + fl] : 0;   // entries 8..15 (uniform guard)
    uint2 v = *(const uint2*)&xb32[(size_t)n * 16 + fl * 2];   // self (pad cols zero)
    float a0 = lo2f(v.x), a1 = hi2f(v.x), a2 = lo2f(v.y), a3 = hi2f(v.y);
    float b0 = 0.f, b1v = 0.f, b2 = 0.f, b3 = 0.f;
    int k = 0;
    if (kA == 8) {                            // 8-deep: 8 rows in flight (58% of rows)
        int s0 = __shfl(stageA, lanebase + 0);
        int s1 = __shfl(stageA, lanebase + 1);
        int s2 = __shfl(stageA, lanebase + 2);
        int s3 = __shfl(stageA, lanebase + 3);
        int s4 = __shfl(stageA, lanebase + 4);
        int s5 = __shfl(stageA, lanebase + 5);
        int s6 = __shfl(stageA, lanebase + 6);
        int s7 = __shfl(stageA, lanebase + 7);
        uint2 v0 = *(const uint2*)&xb32[(size_t)s0 * 16 + fl * 2];
        uint2 v1 = *(const uint2*)&xb32[(size_t)s1 * 16 + fl * 2];
        uint2 v2 = *(const uint2*)&xb32[(size_t)s2 * 16 + fl * 2];
        uint2 v3 = *(const uint2*)&xb32[(size_t)s3 * 16 + fl * 2];
        uint2 v4 = *(const uint2*)&xb32[(size_t)s4 * 16 + fl * 2];
        uint2 v5 = *(const uint2*)&xb32[(size_t)s5 * 16 + fl * 2];
        uint2 v6 = *(const uint2*)&xb32[(size_t)s6 * 16 + fl * 2];
        uint2 v7 = *(const uint2*)&xb32[(size_t)s7 * 16 + fl * 2];
        a0 += lo2f(v0.x); a1 += hi2f(v0.x); a2 += lo2f(v0.y); a3 += hi2f(v0.y);
        b0 += lo2f(v1.x); b1v += hi2f(v1.x); b2 += lo2f(v1.y); b3 += hi2f(v1.y);
        a0 += lo2f(v2.x); a1 += hi2f(v2.x); a2 += lo2f(v2.y); a3 += hi2f(v2.y);
        b0 += lo2f(v3.x); b1v += hi2f(v3.x); b2 += lo2f(v3.y); b3 += hi2f(v3.y);
        a0 += lo2f(v4.x); a1 += hi2f(v4.x); a2 += lo2f(v4.y); a3 += hi2f(v4.y);
        b0 += lo2f(v5.x); b1v += hi2f(v5.x); b2 += lo2f(v5.y); b3 += hi2f(v5.y);
        a0 += lo2f(v6.x); a1 += hi2f(v6.x); a2 += lo2f(v6.y); a3 += hi2f(v6.y);
        b0 += lo2f(v7.x); b1v += hi2f(v7.x); b2 += lo2f(v7.y); b3 += hi2f(v7.y);
        k = 8;
    } else {
        for (; k + 3 < kA; k += 4) {
            int s0 = __shfl(stageA, lanebase + k);
            int s1 = __shfl(stageA, lanebase + k + 1);
            int s2 = __shfl(stageA, lanebase + k + 2);
            int s3 = __shfl(stageA, lanebase + k + 3);
            uint2 v0 = *(const uint2*)&xb32[(size_t)s0 * 16 + fl * 2];
            uint2 v1 = *(const uint2*)&xb32[(size_t)s1 * 16 + fl * 2];
            uint2 v2 = *(const uint2*)&xb32[(size_t)s2 * 16 + fl * 2];
            uint2 v3 = *(const uint2*)&xb32[(size_t)s3 * 16 + fl * 2];
            a0 += lo2f(v0.x); a1 += hi2f(v0.x); a2 += lo2f(v0.y); a3 += hi2f(v0.y);
            b0 += lo2f(v1.x); b1v += hi2f(v1.x); b2 += lo2f(v1.y); b3 += hi2f(v1.y);
            a0 += lo2f(v2.x); a1 += hi2f(v2.x); a2 += lo2f(v2.y); a3 += hi2f(v2.y);
            b0 += lo2f(v3.x); b1v += hi2f(v3.x); b2 += lo2f(v3.y); b3 += hi2f(v3.y);
        }
        for (; k < kA; ++k) {
            int s0 = __shfl(stageA, lanebase + k);
            uint2 v0 = *(const uint2*)&xb32[(size_t)s0 * 16 + fl * 2];
            a0 += lo2f(v0.x); a1 += hi2f(v0.x); a2 += lo2f(v0.y); a3 += hi2f(v0.y);
        }
    }
    for (k = 8; k + 3 < kmax; k += 4) {       // phase B: entries 8..15
        int s0 = __shfl(stageB, lanebase + k - 8);
        int s1 = __shfl(stageB, lanebase + k - 7);
        int s2 = __shfl(stageB, lanebase + k - 6);
        int s3 = __shfl(stageB, lanebase + k - 5);
        uint2 v0 = *(const uint2*)&xb32[(size_t)s0 * 16 + fl * 2];
        uint2 v1 = *(const uint2*)&xb32[(size_t)s1 * 16 + fl * 2];
        uint2 v2 = *(const uint2*)&xb32[(size_t)s2 * 16 + fl * 2];
        uint2 v3 = *(const uint2*)&xb32[(size_t)s3 * 16 + fl * 2];
        a0 += lo2f(v0.x); a1 += hi2f(v0.x); a2 += lo2f(v0.y); a3 += hi2f(v0.y);
        b0 += lo2f(v1.x); b1v += hi2f(v1.x); b2 += lo2f(v1.y); b3 += hi2f(v1.y);
        a0 += lo2f(v2.x); a1 += hi2f(v2.x); a2 += lo2f(v2.y); a3 += hi2f(v2.y);
        b0 += lo2f(v3.x); b1v += hi2f(v3.x); b2 += lo2f(v3.y); b3 += hi2f(v3.y);
    }
    for (; k < kmax && k >= 8; ++k) {
        int s0 = __shfl(stageB, lanebase + k - 8);
        uint2 v0 = *(const uint2*)&xb32[(size_t)s0 * 16 + fl * 2];
        a0 += lo2f(v0.x); a1 += hi2f(v0.x); a2 += lo2f(v0.y); a3 += hi2f(v0.y);
    }
    for (k = 16; k < deg; ++k) {              // deg>16: rare; uniform broadcast loads
        int s0 = csr[rp0 + k];
        uint2 v0 = *(const uint2*)&xb32[(size_t)s0 * 16 + fl * 2];
        a0 += lo2f(v0.x); a1 += hi2f(v0.x); a2 += lo2f(v0.y); a3 += hi2f(v0.y);
    }
    a0 += b0; a1 += b1v; a2 += b2; a3 += b3;
    if (fl < 6) {
        float inv = 1.0f / (float)(deg + 1);
        uint2 o;
        o.x = (u32)f2bf(a0 * inv) | ((u32)f2bf(a1 * inv) << 16);
        o.y = (u32)f2bf(a2 * inv) | ((u32)f2bf(a3 * inv) << 16);
        *(uint2*)&acat32[(size_t)n * 60 + t * 12 + fl * 2] = o;
    }
}

// ------ fused GEMM chain, BARRIER-FREE: one wave owns 16 nodes end-to-end. ------
__global__ __launch_bounds__(256) void k_gemm12(const u16* __restrict__ acat,
                                                const u16* __restrict__ w1t,
                                                const u16* __restrict__ w2t,
                                                const float* __restrict__ b1s,
                                                u16* __restrict__ g) {
    __shared__ u16 s_h1[4][16 * 136];   // per-wave 4352 B  (total 17408)
    __shared__ u16 s_out[4][16 * 72];   // per-wave 2304 B  (total 9216)
    int tid = threadIdx.x;
    int w = tid >> 6, l = tid & 63;
    int lr = l & 15, lg = l >> 4;
    int base = blockIdx.x * 64 + w * 16;         // 16 nodes per wave
    int nrow = base + lr;
    size_t arow = (size_t)(nrow < N_NODES ? nrow : 0) * 120;

    // ---- L1: A-frags straight from acat; k-slice lg=3 (cols 24..31) is zero ----
    short8 a5[5];
    #pragma unroll
    for (int ks = 0; ks < 5; ++ks) {
        short8 av = (short8){0, 0, 0, 0, 0, 0, 0, 0};
        if (lg < 3) av = *(const short8*)&acat[arow + ks * 24 + lg * 8];
        a5[ks] = av;
    }
    {
        f32x4 acc[8];
        #pragma unroll
        for (int nt = 0; nt < 8; ++nt) acc[nt] = (f32x4){0.f, 0.f, 0.f, 0.f};
        #pragma unroll
        for (int nt = 0; nt < 8; ++nt) {
            #pragma unroll
            for (int ks = 0; ks < 5; ++ks) {
                short8 b = *(const short8*)&w1t[(nt * 16 + lr) * 160 + ks * 32 + lg * 8];
                acc[nt] = __builtin_amdgcn_mfma_f32_16x16x32_bf16(a5[ks], b, acc[nt], 0, 0, 0);
            }
        }
        #pragma unroll
        for (int nt = 0; nt < 8; ++nt) {
            float bias = b1s[nt * 16 + lr];
            #pragma unroll
            for (int r = 0; r < 4; ++r) {
                float h = acc[nt][r] + bias;
                s_h1[w][(lg * 4 + r) * 136 + nt * 16 + lr] = f2bf(h > 0.f ? h : 0.f);
            }
        }
    }
    lds_fence();                                  // same-wave h1 write -> read

    // ---- L2: per etype, g_t = h1 @ W2t ----
    short8 a2[4];
    #pragma unroll
    for (int ks = 0; ks < 4; ++ks)
        a2[ks] = *(const short8*)&s_h1[w][lr * 136 + ks * 32 + lg * 8];
    for (int t = 0; t < N_ETYPES; ++t) {
        f32x4 acc2[4];
        #pragma unroll
        for (int nt = 0; nt < 4; ++nt) acc2[nt] = (f32x4){0.f, 0.f, 0.f, 0.f};
        #pragma unroll
        for (int nt = 0; nt < 4; ++nt) {
            #pragma unroll
            for (int ks = 0; ks < 4; ++ks) {
                short8 b = *(const short8*)&w2t[((size_t)t * OUT_DIM + nt * 16 + lr) * HID_DIM + ks * 32 + lg * 8];
                acc2[nt] = __builtin_amdgcn_mfma_f32_16x16x32_bf16(a2[ks], b, acc2[nt], 0, 0, 0);
            }
        }
        lds_fence();                              // prev iteration's s_out reads done
        #pragma unroll
        for (int nt = 0; nt < 4; ++nt)
            #pragma unroll
            for (int r = 0; r < 4; ++r)
                s_out[w][(lg * 4 + r) * 72 + nt * 16 + lr] = f2bf(acc2[nt][r]);
        lds_fence();                              // s_out writes visible to this wave
        size_t pb = (size_t)t * N_NODES;
        #pragma unroll
        for (int j = 0; j < 4; ++j) {
            int i = j * 64 + l;                   // 256 ushort4 chunks = 16 rows x 64 cols
            int row = i >> 4, c4 = (i & 15) * 4;
            int n = base + row;
            if (n < N_NODES)
                *(ushort4*)&g[(pb + n) * OUT_DIM + c4] = *(const ushort4*)&s_out[w][row * 72 + c4];
        }
    }
}

// ------ layer-2 gather: 16-lane group per node (4 nodes/wave); lane owns uint2 (4 bf16).
// ------ 8-deep phase-A unroll; bounds group-uniform -> shfl always uniform.
__global__ __launch_bounds__(256) void k_gather2(const int* __restrict__ rowptr,
                                                 const int* __restrict__ csr,
                                                 const u32* __restrict__ g32,
                                                 u32* __restrict__ h232) {
    int tid = threadIdx.x;
    int fl = tid & 15;                        // uint2 index within 128B row
    int lanebase = tid & 48;                  // 16-lane group base within wave
    int n = blockIdx.x * 16 + (tid >> 4);     // 16 nodes per block
    int kb = n * N_ETYPES;
    float acc0 = 0.f, acc1 = 0.f, acc2 = 0.f, acc3 = 0.f;
    for (int tc = 0; tc < N_ETYPES; ++tc) {
        int rp0 = rowptr[kb + tc];
        int deg = rowptr[kb + tc + 1] - rp0;
        int kmax = deg < 32 ? deg : 32;
        int kA = kmax < 16 ? kmax : 16;
        int stageA = csr[rp0 + fl];           // entries 0..15
        int stageB = (kmax > 16) ? csr[rp0 + 16 + fl] : 0;   // uniform guard
        const u32* gp = g32 + (size_t)tc * N_NODES * 32;
        uint2 v = *(const uint2*)&gp[(size_t)n * 32 + fl * 2];    // self
        float s0 = lo2f(v.x), s1 = hi2f(v.x), s2 = lo2f(v.y), s3 = hi2f(v.y);
        float r0 = 0.f, r1 = 0.f, r2 = 0.f, r3 = 0.f;
        int k = 0;
        for (; k + 7 < kA; k += 8) {          // 8 rows in flight
            int p0 = __shfl(stageA, lanebase + k);
            int p1 = __shfl(stageA, lanebase + k + 1);
            int p2 = __shfl(stageA, lanebase + k + 2);
            int p3 = __shfl(stageA, lanebase + k + 3);
            int p4 = __shfl(stageA, lanebase + k + 4);
            int p5 = __shfl(stageA, lanebase + k + 5);
            int p6 = __shfl(stageA, lanebase + k + 6);
            int p7 = __shfl(stageA, lanebase + k + 7);
            uint2 v0 = *(const uint2*)&gp[(size_t)p0 * 32 + fl * 2];
            uint2 v1 = *(const uint2*)&gp[(size_t)p1 * 32 + fl * 2];
            uint2 v2 = *(const uint2*)&gp[(size_t)p2 * 32 + fl * 2];
            uint2 v3 = *(const uint2*)&gp[(size_t)p3 * 32 + fl * 2];
            uint2 v4 = *(const uint2*)&gp[(size_t)p4 * 32 + fl * 2];
            uint2 v5 = *(const uint2*)&gp[(size_t)p5 * 32 + fl * 2];
            uint2 v6 = *(const uint2*)&gp[(size_t)p6 * 32 + fl * 2];
            uint2 v7 = *(const uint2*)&gp[(size_t)p7 * 32 + fl * 2];
            s0 += lo2f(v0.x); s1 += hi2f(v0.x); s2 += lo2f(v0.y); s3 += hi2f(v0.y);
            r0 += lo2f(v1.x); r1 += hi2f(v1.x); r2 += lo2f(v1.y); r3 += hi2f(v1.y);
            s0 += lo2f(v2.x); s1 += hi2f(v2.x); s2 += lo2f(v2.y); s3 += hi2f(v2.y);
            r0 += lo2f(v3.x); r1 += hi2f(v3.x); r2 += lo2f(v3.y); r3 += hi2f(v3.y);
            s0 += lo2f(v4.x); s1 += hi2f(v4.x); s2 += lo2f(v4.y); s3 += hi2f(v4.y);
            r0 += lo2f(v5.x); r1 += hi2f(v5.x); r2 += lo2f(v5.y); r3 += hi2f(v5.y);
            s0 += lo2f(v6.x); s1 += hi2f(v6.x); s2 += lo2f(v6.y); s3 += hi2f(v6.y);
            r0 += lo2f(v7.x); r1 += hi2f(v7.x); r2 += lo2f(v7.y); r3 += hi2f(v7.y);
        }
        for (; k + 3 < kA; k += 4) {          // 4 rows in flight
            int p0 = __shfl(stageA, lanebase + k);
            int p1 = __shfl(stageA, lanebase + k + 1);
            int p2 = __shfl(stageA, lanebase + k + 2);
            int p3 = __shfl(stageA, lanebase + k + 3);
            uint2 v0 = *(const uint2*)&gp[(size_t)p0 * 32 + fl * 2];
            uint2 v1 = *(const uint2*)&gp[(size_t)p1 * 32 + fl * 2];
            uint2 v2 = *(const uint2*)&gp[(size_t)p2 * 32 + fl * 2];
            uint2 v3 = *(const uint2*)&gp[(size_t)p3 * 32 + fl * 2];
            s0 += lo2f(v0.x); s1 += hi2f(v0.x); s2 += lo2f(v0.y); s3 += hi2f(v0.y);
            r0 += lo2f(v1.x); r1 += hi2f(v1.x); r2 += lo2f(v1.y); r3 += hi2f(v1.y);
            s0 += lo2f(v2.x); s1 += hi2f(v2.x); s2 += lo2f(v2.y); s3 += hi2f(v2.y);
            r0 += lo2f(v3.x); r1 += hi2f(v3.x); r2 += lo2f(v3.y); r3 += hi2f(v3.y);
        }
        for (; k < kA; ++k) {
            int p0 = __shfl(stageA, lanebase + k);
            uint2 v0 = *(const uint2*)&gp[(size_t)p0 * 32 + fl * 2];
            s0 += lo2f(v0.x); s1 += hi2f(v0.x); s2 += lo2f(v0.y); s3 += hi2f(v0.y);
        }
        for (k = 16; k + 3 < kmax; k += 4) {  // phase B: entries 16..31
            int p0 = __shfl(stageB, lanebase + k - 16);
            int p1 = __shfl(stageB, lanebase + k - 15);
            int p2 = __shfl(stageB, lanebase + k - 14);
            int p3 = __shfl(stageB, lanebase + k - 13);
            uint2 v0 = *(const uint2*)&gp[(size_t)p0 * 32 + fl * 2];
            uint2 v1 = *(const uint2*)&gp[(size_t)p1 * 32 + fl * 2];
            uint2 v2 = *(const uint2*)&gp[(size_t)p2 * 32 + fl * 2];
            uint2 v3 = *(const uint2*)&gp[(size_t)p3 * 32 + fl * 2];
            s0 += lo2f(v0.x); s1 += hi2f(v0.x); s2 += lo2f(v0.y); s3 += hi2f(v0.y);
            r0 += lo2f(v1.x); r1 += hi2f(v1.x); r2 += lo2f(v1.y); r3 += hi2f(v1.y);
            s0 += lo2f(v2.x); s1 += hi2f(v2.x); s2 += lo2f(v2.y); s3 += hi2f(v2.y);
            r0 += lo2f(v3.x); r1 += hi2f(v3.x); r2 += lo2f(v3.y); r3 += hi2f(v3.y);
        }
        for (; k < kmax && k >= 16; ++k) {
            int p0 = __shfl(stageB, lanebase + k - 16);
            uint2 v0 = *(const uint2*)&gp[(size_t)p0 * 32 + fl * 2];
            s0 += lo2f(v0.x); s1 += hi2f(v0.x); s2 += lo2f(v0.y); s3 += hi2f(v0.y);
        }
        for (k = 32; k < deg; ++k) {          // deg>32: ~never; uniform broadcast loads
            int p0 = csr[rp0 + k];
            uint2 v0 = *(const uint2*)&gp[(size_t)p0 * 32 + fl * 2];
            s0 += lo2f(v0.x); s1 += hi2f(v0.x); s2 += lo2f(v0.y); s3 += hi2f(v0.y);
        }
        float inv = 1.0f / (float)(deg + 1);
        acc0 = fmaf(s0 + r0, inv, acc0);
        acc1 = fmaf(s1 + r1, inv, acc1);
        acc2 = fmaf(s2 + r2, inv, acc2);
        acc3 = fmaf(s3 + r3, inv, acc3);
    }
    uint2 o;
    o.x = (u32)f2bf(acc0) | ((u32)f2bf(acc1) << 16);
    o.y = (u32)f2bf(acc2) | ((u32)f2bf(acc3) << 16);
    *(uint2*)&h232[(size_t)n * 32 + fl * 2] = o;
}

// ---------------- pooling stage 1: chunked partial sums (sorted gids -> few atomics) -------
__global__ __launch_bounds__(256) void k_pool1(const u16* __restrict__ h2,
                                               const int* __restrict__ gids,
                                               float* __restrict__ out_acc) {
    int w = threadIdx.x >> 6, lane = threadIdx.x & 63;
    int n0 = blockIdx.x * 256 + w * 64;
    int nend = n0 + 64; if (nend > N_NODES) nend = N_NODES;
    float acc = 0.f;
    int cur = -1;
    for (int n = n0; n < nend; ++n) {
        int gid = gids[n];
        if (gid != cur) {
            if (cur >= 0) atomicAdd(&out_acc[cur * OUT_DIM + lane], acc);
            acc = 0.f; cur = gid;
        }
        acc += bf2f(h2[(size_t)n * OUT_DIM + lane]);
    }
    if (cur >= 0) atomicAdd(&out_acc[cur * OUT_DIM + lane], acc);
}

// ---------------- pooling stage 2: divide by count, add bias ----------------
__global__ __launch_bounds__(64) void k_pool2(const float* __restrict__ out_acc,
                                              const int* __restrict__ gids,
                                              const float* __restrict__ b2,
                                              float* __restrict__ out) {
    int gid = blockIdx.x, j = threadIdx.x;
    int lo = 0, hi = N_NODES;
    while (lo < hi) { int mid = (lo + hi) >> 1; if (gids[mid] < gid) lo = mid + 1; else hi = mid; }
    int start = lo;
    hi = N_NODES;
    while (lo < hi) { int mid = (lo + hi) >> 1; if (gids[mid] < gid + 1) lo = mid + 1; else hi = mid; }
    int count = lo - start;
    float b = 0.f;
    #pragma unroll
    for (int t = 0; t < N_ETYPES; ++t) b += b2[t * OUT_DIM + j];
    float c = (float)count;
    out[gid * OUT_DIM + j] = (out_acc[gid * OUT_DIM + j] + c * b) / fmaxf(c, 1.0f);
}

extern "C" void kernel_launch(void* const* d_in, const int* in_sizes, int n_in,
                              void* d_out, int out_size, void* d_ws, size_t ws_size,
                              hipStream_t stream) {
    const float* x    = (const float*)d_in[0];
    const int*   edges= (const int*)d_in[1];
    const int*   gids = (const int*)d_in[2];
    const float* W1   = (const float*)d_in[3];
    const float* b1   = (const float*)d_in[4];
    const float* W2   = (const float*)d_in[5];
    const float* b2   = (const float*)d_in[6];
    float* out = (float*)d_out;

    // word-offset (u32) workspace layout; total 31,335,296 words = 125.3 MB (audited r10)
    int*   bin_cnt = (int*)d_ws;                          // 0       (256)
    int*   rowptr  = bin_cnt + 256;                       // 256     (500,016)
    int*   csr     = bin_cnt + 500272;                    // 500,272 (4,000,080)
    u16*   xb      = (u16*)(bin_cnt + 4500352);           // 4,500,352 (1,600,000 u16 = 800,000 w)
    u16*   w1t     = (u16*)(bin_cnt + 6100352);           // 6,100,352 (20,480 u16 = 10,240 w)
    u16*   w2t     = (u16*)(bin_cnt + 6110592);           // 6,110,592 (40,960 u16 = 20,480 w)
    float* b1s     = (float*)(bin_cnt + 6131072);         // 6,131,072 (128, pad to 6,131,200)
    u16*   acat    = (u16*)(bin_cnt + 6131200);           // 6,131,200 (12,000,000 u16 = 6,000,000 w)
    u16*   g       = (u16*)(bin_cnt + 12131200);          // 12,131,200 (32,000,000 u16 = 16,000,000 w)
    int*   binned  = bin_cnt + 12131200;                  // alias over g head (4,515,840 w)
    u16*   h2      = (u16*)(bin_cnt + 28131200);          // 28,131,200 (6,400,000 u16 = 3,200,000 w)
    float* out_acc = (float*)(bin_cnt + 31331200);        // 31,331,200 (4,096)

    hipMemsetAsync(bin_cnt, 0, 256 * sizeof(int), stream);
    hipMemsetAsync(out_acc, 0, NUM_GRAPHS * OUT_DIM * sizeof(float), stream);

    k_prep<<<1024, 256, 0, stream>>>(W1, W2, b1, x, w1t, w2t, b1s, xb);
    k_bin<<<(TOT_EDGES + CHUNK - 1) / CHUNK, 256, 0, stream>>>(edges, bin_cnt, binned);
    k_csr<<<NBINS, 256, 0, stream>>>(bin_cnt, binned, rowptr, csr);

    k_gather1<<<dim3(N_NODES / 32, N_ETYPES), 256, 0, stream>>>(
        rowptr, csr, (const u32*)xb, (u32*)acat);

    int nblk = (N_NODES + 63) / 64;
    k_gemm12<<<nblk, 256, 0, stream>>>(acat, w1t, w2t, b1s, g);
    k_gather2<<<N_NODES / 16, 256, 0, stream>>>(rowptr, csr, (const u32*)g, (u32*)h2);

    k_pool1<<<(N_NODES + 255) / 256, 256, 0, stream>>>(h2, gids, out_acc);
    k_pool2<<<NUM_GRAPHS, 64, 0, stream>>>(out_acc, gids, b2, out);
}